// Round 4
// baseline (446.496 us; speedup 1.0000x reference)
//
#include <hip/hip_runtime.h>
#include <hip/hip_bf16.h>
#include <math.h>

#define BT    1024   // B*T
#define NH    8
#define NSEG  8
#define NBH   16     // B*H

// ---------------- GEMM: X(f32) @ W(f32) -> C(f32), 1024^3, fused over 4 weights ----------------
__global__ __launch_bounds__(256) void proj_gemm(
    const float* __restrict__ X,
    const float* __restrict__ Wq, const float* __restrict__ Wk,
    const float* __restrict__ Wv, const float* __restrict__ Wg,
    float* __restrict__ Qo, float* __restrict__ Ko,
    float* __restrict__ Vo, float* __restrict__ Go)
{
    const int z = blockIdx.z;
    const float* W = (z == 0) ? Wq : (z == 1) ? Wk : (z == 2) ? Wv : Wg;
    float* C       = (z == 0) ? Qo : (z == 1) ? Ko : (z == 2) ? Vo : Go;
    const float scale = (z == 0) ? 0.08838834764831845f : 1.0f;  // HK^-0.5 on q

    __shared__ __align__(16) float As[16][64];
    __shared__ __align__(16) float Bs[16][64];
    const int tid = threadIdx.x;
    const int tx = tid & 15, ty = tid >> 4;
    const int m0 = blockIdx.y * 64, n0 = blockIdx.x * 64;
    const int ar = tid >> 2, ac = (tid & 3) << 2;   // A stage: 64 rows x 16 cols
    const int br = ty, bc = tx << 2;                // B stage: 16 rows x 64 cols
    float acc[4][4] = {};

    for (int kb = 0; kb < 1024; kb += 16) {
        float4 fa = *(const float4*)(X + (size_t)(m0 + ar) * 1024 + kb + ac);
        As[ac + 0][ar] = fa.x; As[ac + 1][ar] = fa.y; As[ac + 2][ar] = fa.z; As[ac + 3][ar] = fa.w;
        float4 fb = *(const float4*)(W + (size_t)(kb + br) * 1024 + n0 + bc);
        Bs[br][bc + 0] = fb.x; Bs[br][bc + 1] = fb.y; Bs[br][bc + 2] = fb.z; Bs[br][bc + 3] = fb.w;
        __syncthreads();
        #pragma unroll
        for (int kk = 0; kk < 16; kk++) {
            float4 av = *(const float4*)&As[kk][ty << 2];
            float4 bv = *(const float4*)&Bs[kk][tx << 2];
            float a[4] = {av.x, av.y, av.z, av.w};
            float b[4] = {bv.x, bv.y, bv.z, bv.w};
            #pragma unroll
            for (int i = 0; i < 4; i++)
                #pragma unroll
                for (int j = 0; j < 4; j++)
                    acc[i][j] = fmaf(a[i], b[j], acc[i][j]);
        }
        __syncthreads();
    }
    #pragma unroll
    for (int i = 0; i < 4; i++)
        #pragma unroll
        for (int j = 0; j < 4; j++)
            C[(size_t)(m0 + (ty << 2) + i) * 1024 + n0 + (tx << 2) + j] = acc[i][j] * scale;
}

// ---------------- GEMM: NR(f32) @ Wo(f32) -> out(f32) ----------------
__global__ __launch_bounds__(256) void wo_gemm(
    const float* __restrict__ A, const float* __restrict__ W, float* __restrict__ C)
{
    __shared__ __align__(16) float As[16][64];
    __shared__ __align__(16) float Bs[16][64];
    const int tid = threadIdx.x;
    const int tx = tid & 15, ty = tid >> 4;
    const int m0 = blockIdx.y * 64, n0 = blockIdx.x * 64;
    const int ar = tid >> 2, ac = (tid & 3) << 2;
    const int br = ty, bc = tx << 2;
    float acc[4][4] = {};

    for (int kb = 0; kb < 1024; kb += 16) {
        float4 fa = *(const float4*)(A + (size_t)(m0 + ar) * 1024 + kb + ac);
        As[ac + 0][ar] = fa.x; As[ac + 1][ar] = fa.y; As[ac + 2][ar] = fa.z; As[ac + 3][ar] = fa.w;
        float4 fb = *(const float4*)(W + (size_t)(kb + br) * 1024 + n0 + bc);
        Bs[br][bc + 0] = fb.x; Bs[br][bc + 1] = fb.y; Bs[br][bc + 2] = fb.z; Bs[br][bc + 3] = fb.w;
        __syncthreads();
        #pragma unroll
        for (int kk = 0; kk < 16; kk++) {
            float4 av = *(const float4*)&As[kk][ty << 2];
            float4 bv = *(const float4*)&Bs[kk][tx << 2];
            float a[4] = {av.x, av.y, av.z, av.w};
            float b[4] = {bv.x, bv.y, bv.z, bv.w};
            #pragma unroll
            for (int i = 0; i < 4; i++)
                #pragma unroll
                for (int j = 0; j < 4; j++)
                    acc[i][j] = fmaf(a[i], b[j], acc[i][j]);
        }
        __syncthreads();
    }
    #pragma unroll
    for (int i = 0; i < 4; i++)
        #pragma unroll
        for (int j = 0; j < 4; j++)
            C[(size_t)(m0 + (ty << 2) + i) * 1024 + n0 + (tx << 2) + j] = acc[i][j];
}

// ---------------- low-rank gate: gk = logsigmoid(x@Wgk1@Wgk2 + b)/16 ----------------
__global__ __launch_bounds__(256) void gk_proj(
    const float* __restrict__ X, const float* __restrict__ Wgk1,
    const float* __restrict__ Wgk2, const float* __restrict__ bgk2,
    float* __restrict__ GK)
{
    const int row = blockIdx.x, tid = threadIdx.x;
    float p[16];
    #pragma unroll
    for (int j = 0; j < 16; j++) p[j] = 0.f;
    for (int d = tid; d < 1024; d += 256) {
        float xv = X[(size_t)row * 1024 + d];
        #pragma unroll
        for (int j = 0; j < 16; j++)
            p[j] = fmaf(xv, Wgk1[d * 16 + j], p[j]);
    }
    #pragma unroll
    for (int j = 0; j < 16; j++)
        for (int off = 32; off; off >>= 1) p[j] += __shfl_down(p[j], off);
    __shared__ float zp[4][16];
    __shared__ float z[16];
    const int lane = tid & 63, w = tid >> 6;
    if (lane == 0) {
        #pragma unroll
        for (int j = 0; j < 16; j++) zp[w][j] = p[j];
    }
    __syncthreads();
    if (tid < 16) z[tid] = zp[0][tid] + zp[1][tid] + zp[2][tid] + zp[3][tid];
    __syncthreads();
    for (int c = tid; c < 1024; c += 256) {
        float acc = bgk2[c];
        #pragma unroll
        for (int j = 0; j < 16; j++)
            acc = fmaf(z[j], Wgk2[j * 1024 + c], acc);
        float ls = fminf(acc, 0.f) - log1pf(expf(-fabsf(acc)));  // logsigmoid
        GK[(size_t)row * 1024 + c] = ls * (1.f / 16.f);
    }
}

// ---------------- phase A: per-segment local scan (S starts at 0) ----------------
__global__ __launch_bounds__(256) void scan_local(
    const float* __restrict__ Q, const float* __restrict__ K,
    const float* __restrict__ V, const float* __restrict__ GK,
    float* __restrict__ O, float* __restrict__ SS, float* __restrict__ DSEG)
{
    const int seg = blockIdx.x;   // 0..7
    const int bh  = blockIdx.y;   // 0..15
    const int b = bh >> 3, h = bh & 7;
    const int tid = threadIdx.x;
    const int v = tid & 127, kh = tid >> 7;
    const int k0 = kh << 6;
    __shared__ float4 dkq[128];
    __shared__ float red[128];
    float s[64];
    #pragma unroll
    for (int i = 0; i < 64; i++) s[i] = 0.f;
    float gsum = 0.f;
    const size_t rowbase = (size_t)(b * 512 + seg * 64) * 1024 + h * 128;

    for (int t = 0; t < 64; t++) {
        const size_t base = rowbase + (size_t)t * 1024;
        if (tid < 128) {
            float gkv = GK[base + tid];
            gsum += gkv;
            dkq[tid] = make_float4(expf(gkv), K[base + tid], Q[base + tid], 0.f);
        }
        float vv = V[base + v];
        __syncthreads();             // barrier A: dkq ready
        float acc = 0.f;
        #pragma unroll
        for (int i = 0; i < 64; i++) {
            float4 d4 = dkq[k0 + i];
            s[i] = fmaf(s[i], d4.x, d4.y * vv);
            acc  = fmaf(d4.z, s[i], acc);
        }
        if (kh) red[v] = acc;
        __syncthreads();             // barrier B: red ready, dkq reads done
        if (!kh) O[base + v] = acc + red[v];
    }
    const size_t sbase = (size_t)(bh * 8 + seg) * 16384;
    #pragma unroll
    for (int i = 0; i < 64; i++) SS[sbase + (size_t)(k0 + i) * 128 + v] = s[i];
    if (tid < 128) DSEG[(bh * 8 + seg) * 128 + tid] = expf(gsum);
}

// ---------------- phase B: stitch segment states; SS becomes S_in per segment ----------------
__global__ __launch_bounds__(256) void stitch(
    float* __restrict__ SS, const float* __restrict__ DSEG)
{
    const int bh = blockIdx.x, tid = threadIdx.x;
    __shared__ float dbuf[128];
    float srun[64];
    #pragma unroll
    for (int j = 0; j < 64; j++) srun[j] = 0.f;
    for (int seg = 0; seg < 8; seg++) {
        if (tid < 128) dbuf[tid] = DSEG[(bh * 8 + seg) * 128 + tid];
        __syncthreads();
        const size_t base = (size_t)(bh * 8 + seg) * 16384;
        #pragma unroll
        for (int j = 0; j < 64; j++) {
            const int e = j * 256 + tid;
            float tmp = SS[base + e];
            SS[base + e] = srun[j];              // S_in for this segment
            srun[j] = fmaf(srun[j], dbuf[e >> 7], tmp);
        }
        __syncthreads();
    }
}

// ---------------- phase C: o_t += (q_t * exp(Gcum_t)) @ S_in ----------------
__global__ __launch_bounds__(256) void correction(
    const float* __restrict__ Q, const float* __restrict__ GK,
    const float* __restrict__ SS, float* __restrict__ O)
{
    const int seg = blockIdx.x + 1;  // seg 0 has S_in = 0
    const int bh = blockIdx.y;
    const int b = bh >> 3, h = bh & 7;
    const int tid = threadIdx.x;
    __shared__ float qt[64][128];
    const size_t rowbase = (size_t)(b * 512 + seg * 64) * 1024 + h * 128;
    if (tid < 128) {
        float gsumc = 0.f;
        for (int t = 0; t < 64; t++) {
            const size_t base = rowbase + (size_t)t * 1024;
            gsumc += GK[base + tid];
            qt[t][tid] = Q[base + tid] * expf(gsumc);
        }
    }
    __syncthreads();
    const size_t sbase = (size_t)(bh * 8 + seg) * 16384;
    const int v = tid & 127, th = tid >> 7;  // th: half of t-range
    float acc[32];
    #pragma unroll
    for (int tt = 0; tt < 32; tt++) acc[tt] = 0.f;
    for (int k = 0; k < 128; k++) {
        float sv = SS[sbase + (size_t)k * 128 + v];
        #pragma unroll
        for (int tt = 0; tt < 32; tt++)
            acc[tt] = fmaf(qt[th * 32 + tt][k], sv, acc[tt]);
    }
    #pragma unroll
    for (int tt = 0; tt < 32; tt++) {
        const int t = th * 32 + tt;
        O[rowbase + (size_t)t * 1024 + v] += acc[tt];
    }
}

// ---------------- gated RMSNorm (in-place on O) ----------------
__global__ __launch_bounds__(128) void gnorm(
    const float* __restrict__ O, const float* __restrict__ G,
    const float* __restrict__ gnw, float* __restrict__ NR)
{
    const int row = blockIdx.x;          // (b*T + t)*H + h
    const int bt = row >> 3, h = row & 7;
    const int v = threadIdx.x;
    const size_t idx = (size_t)bt * 1024 + h * 128 + v;
    float o = O[idx];
    float ss = o * o;
    for (int off = 32; off; off >>= 1) ss += __shfl_down(ss, off);
    __shared__ float w2[2];
    if ((v & 63) == 0) w2[v >> 6] = ss;
    __syncthreads();
    float ms = (w2[0] + w2[1]) * (1.f / 128.f);
    float r = rsqrtf(ms + 1e-5f);
    float g = G[idx];
    float sg = g / (1.f + expf(-g));     // g * sigmoid(g)
    NR[idx] = o * r * gnw[v] * sg;
}

extern "C" void kernel_launch(void* const* d_in, const int* in_sizes, int n_in,
                              void* d_out, int out_size, void* d_ws, size_t ws_size,
                              hipStream_t stream)
{
    const float* X    = (const float*)d_in[0];
    const float* Wq   = (const float*)d_in[1];
    const float* Wk   = (const float*)d_in[2];
    const float* Wv   = (const float*)d_in[3];
    const float* Wg   = (const float*)d_in[4];
    const float* Wgk1 = (const float*)d_in[5];
    const float* Wgk2 = (const float*)d_in[6];
    const float* bgk2 = (const float*)d_in[7];
    const float* gnw  = (const float*)d_in[8];
    const float* Wo   = (const float*)d_in[9];
    float* OUT = (float*)d_out;   // reference output is float32

    float* ws = (float*)d_ws;
    float* Qb  = ws;                 // 1M f32 each
    float* Kb  = ws + (1u << 20);
    float* Vb  = ws + (2u << 20);
    float* Gb  = ws + (3u << 20);
    float* GKb = ws + (4u << 20);
    float* Ob  = ws + (5u << 20);
    float* SS  = ws + (6u << 20);    // 2M f32 (16 bh x 8 seg x 128 x 128)
    float* DS  = ws + (8u << 20);    // 16K f32

    proj_gemm<<<dim3(16, 16, 4), 256, 0, stream>>>(X, Wq, Wk, Wv, Wg, Qb, Kb, Vb, Gb);
    gk_proj<<<dim3(BT), 256, 0, stream>>>(X, Wgk1, Wgk2, bgk2, GKb);
    scan_local<<<dim3(NSEG, NBH), 256, 0, stream>>>(Qb, Kb, Vb, GKb, Ob, SS, DS);
    stitch<<<dim3(NBH), 256, 0, stream>>>(SS, DS);
    correction<<<dim3(NSEG - 1, NBH), 256, 0, stream>>>(Qb, GKb, SS, Ob);
    gnorm<<<dim3(BT * NH), 128, 0, stream>>>(Ob, Gb, gnw, Ob);
    wo_gemm<<<dim3(16, 16), 256, 0, stream>>>(Ob, Wo, OUT);
}

// Round 5
// 338.617 us; speedup vs baseline: 1.3186x; 1.3186x over previous
//
#include <hip/hip_runtime.h>
#include <hip/hip_bf16.h>
#include <math.h>

#define BT    1024   // B*T
#define NH    8
#define NSEG  8
#define NBH   16     // B*H

typedef __attribute__((ext_vector_type(8))) short short8;
typedef __attribute__((ext_vector_type(4))) float f32x4;

__device__ __forceinline__ float bitf(short u) {
    union { float f; unsigned i; } x; x.i = ((unsigned)(unsigned short)u) << 16; return x.f;
}
__device__ __forceinline__ short f2bf(float f) {   // RNE f32->bf16
    union { float f; unsigned u; } x; x.f = f;
    unsigned r = x.u + 0x7FFF + ((x.u >> 16) & 1);
    return (short)(r >> 16);
}

// ---------------- transpose+cast: W[k][n] f32 -> WT[n][k] bf16, 5 weights ----------------
__global__ __launch_bounds__(256) void cast_wt(
    const float* __restrict__ Wq, const float* __restrict__ Wk,
    const float* __restrict__ Wv, const float* __restrict__ Wg,
    const float* __restrict__ Wo, short* __restrict__ WT)
{
    const int z = blockIdx.z;
    const float* W = (z == 0) ? Wq : (z == 1) ? Wk : (z == 2) ? Wv : (z == 3) ? Wg : Wo;
    short* T = WT + (size_t)z * (1u << 20);
    __shared__ float tile[32][33];
    const int tid = threadIdx.x;
    const int k0 = blockIdx.y * 32, n0 = blockIdx.x * 32;
    const int row = tid >> 3, c4 = (tid & 7) << 2;
    float4 f = *(const float4*)(W + (size_t)(k0 + row) * 1024 + n0 + c4);
    tile[row][c4 + 0] = f.x; tile[row][c4 + 1] = f.y;
    tile[row][c4 + 2] = f.z; tile[row][c4 + 3] = f.w;
    __syncthreads();
    short* o = T + (size_t)(n0 + row) * 1024 + k0 + c4;
    o[0] = f2bf(tile[c4 + 0][row]); o[1] = f2bf(tile[c4 + 1][row]);
    o[2] = f2bf(tile[c4 + 2][row]); o[3] = f2bf(tile[c4 + 3][row]);
}

// ---------------- MFMA GEMM: X(f32)@W -> bf16 out, fused over 4 weights ----------------
// A in LDS: As[kb][m][8] (k-contiguous 8 bf16 = 16B per entry); same for B (from WT[n][k]).
__global__ __launch_bounds__(256) void proj_gemm(
    const float* __restrict__ X, const short* __restrict__ WT,
    short* __restrict__ QKVG)
{
    const int z = blockIdx.z;
    const float scale = (z == 0) ? 0.08838834764831845f : 1.0f;  // HK^-0.5 on q
    short* C = QKVG + (size_t)z * (1u << 20);
    const short* B = WT + (size_t)z * (1u << 20);

    __shared__ __align__(16) short As[8 * 128 * 8];  // 16 KB
    __shared__ __align__(16) short Bs[8 * 128 * 8];  // 16 KB
    const int tid = threadIdx.x;
    const int wave = tid >> 6, lane = tid & 63;
    const int wm = (wave >> 1) * 64, wn = (wave & 1) * 64;
    const int m15 = lane & 15, q = lane >> 4;
    const int m0 = blockIdx.y * 128, n0 = blockIdx.x * 128;
    const int r = tid & 127, kh = tid >> 7;

    f32x4 acc[4][4];
    #pragma unroll
    for (int i = 0; i < 4; i++)
        #pragma unroll
        for (int j = 0; j < 4; j++)
            acc[i][j] = (f32x4){0.f, 0.f, 0.f, 0.f};

    for (int kb0 = 0; kb0 < 1024; kb0 += 64) {
        __syncthreads();
        // stage A: rows m0+r, k = kb0 + kh*32 .. +32, f32 -> bf16
        {
            const float4* src = (const float4*)(X + (size_t)(m0 + r) * 1024 + kb0 + kh * 32);
            #pragma unroll
            for (int jj = 0; jj < 4; jj++) {
                float4 fa = src[2 * jj], fb = src[2 * jj + 1];
                short8 v;
                v[0] = f2bf(fa.x); v[1] = f2bf(fa.y); v[2] = f2bf(fa.z); v[3] = f2bf(fa.w);
                v[4] = f2bf(fb.x); v[5] = f2bf(fb.y); v[6] = f2bf(fb.z); v[7] = f2bf(fb.w);
                *(short8*)&As[(((kh << 2) + jj) * 128 + r) * 8] = v;
            }
        }
        // stage B: WT rows n0+r, same k range (already bf16)
        {
            const short8* src = (const short8*)(B + (size_t)(n0 + r) * 1024 + kb0 + kh * 32);
            #pragma unroll
            for (int jj = 0; jj < 4; jj++)
                *(short8*)&Bs[(((kh << 2) + jj) * 128 + r) * 8] = src[jj];
        }
        __syncthreads();
        #pragma unroll
        for (int s = 0; s < 2; s++) {
            short8 af[4], bf[4];
            const int kq = ((s << 2) + q) * 128;
            #pragma unroll
            for (int i = 0; i < 4; i++)
                af[i] = *(const short8*)&As[(kq + wm + i * 16 + m15) * 8];
            #pragma unroll
            for (int j = 0; j < 4; j++)
                bf[j] = *(const short8*)&Bs[(kq + wn + j * 16 + m15) * 8];
            #pragma unroll
            for (int i = 0; i < 4; i++)
                #pragma unroll
                for (int j = 0; j < 4; j++)
                    acc[i][j] = __builtin_amdgcn_mfma_f32_16x16x32_bf16(af[i], bf[j], acc[i][j], 0, 0, 0);
        }
    }
    // D layout: row = q*4 + reg, col = m15
    #pragma unroll
    for (int i = 0; i < 4; i++)
        #pragma unroll
        for (int j = 0; j < 4; j++)
            #pragma unroll
            for (int rr = 0; rr < 4; rr++)
                C[(size_t)(m0 + wm + i * 16 + q * 4 + rr) * 1024 + n0 + wn + j * 16 + m15] =
                    f2bf(acc[i][j][rr] * scale);
}

// ---------------- MFMA GEMM: Obf(bf16)@WoT -> out f32 ----------------
__global__ __launch_bounds__(256) void wo_gemm(
    const short* __restrict__ A, const short* __restrict__ B, float* __restrict__ C)
{
    __shared__ __align__(16) short As[8 * 128 * 8];
    __shared__ __align__(16) short Bs[8 * 128 * 8];
    const int tid = threadIdx.x;
    const int wave = tid >> 6, lane = tid & 63;
    const int wm = (wave >> 1) * 64, wn = (wave & 1) * 64;
    const int m15 = lane & 15, q = lane >> 4;
    const int m0 = blockIdx.y * 128, n0 = blockIdx.x * 128;
    const int r = tid & 127, kh = tid >> 7;

    f32x4 acc[4][4];
    #pragma unroll
    for (int i = 0; i < 4; i++)
        #pragma unroll
        for (int j = 0; j < 4; j++)
            acc[i][j] = (f32x4){0.f, 0.f, 0.f, 0.f};

    for (int kb0 = 0; kb0 < 1024; kb0 += 64) {
        __syncthreads();
        {
            const short8* src = (const short8*)(A + (size_t)(m0 + r) * 1024 + kb0 + kh * 32);
            #pragma unroll
            for (int jj = 0; jj < 4; jj++)
                *(short8*)&As[(((kh << 2) + jj) * 128 + r) * 8] = src[jj];
        }
        {
            const short8* src = (const short8*)(B + (size_t)(n0 + r) * 1024 + kb0 + kh * 32);
            #pragma unroll
            for (int jj = 0; jj < 4; jj++)
                *(short8*)&Bs[(((kh << 2) + jj) * 128 + r) * 8] = src[jj];
        }
        __syncthreads();
        #pragma unroll
        for (int s = 0; s < 2; s++) {
            short8 af[4], bf[4];
            const int kq = ((s << 2) + q) * 128;
            #pragma unroll
            for (int i = 0; i < 4; i++)
                af[i] = *(const short8*)&As[(kq + wm + i * 16 + m15) * 8];
            #pragma unroll
            for (int j = 0; j < 4; j++)
                bf[j] = *(const short8*)&Bs[(kq + wn + j * 16 + m15) * 8];
            #pragma unroll
            for (int i = 0; i < 4; i++)
                #pragma unroll
                for (int j = 0; j < 4; j++)
                    acc[i][j] = __builtin_amdgcn_mfma_f32_16x16x32_bf16(af[i], bf[j], acc[i][j], 0, 0, 0);
        }
    }
    #pragma unroll
    for (int i = 0; i < 4; i++)
        #pragma unroll
        for (int j = 0; j < 4; j++)
            #pragma unroll
            for (int rr = 0; rr < 4; rr++)
                C[(size_t)(m0 + wm + i * 16 + q * 4 + rr) * 1024 + n0 + wn + j * 16 + m15] =
                    acc[i][j][rr];
}

// ---------------- low-rank gate: gk = logsigmoid(x@Wgk1@Wgk2 + b)/16 -> bf16 ----------------
__global__ __launch_bounds__(256) void gk_proj(
    const float* __restrict__ X, const float* __restrict__ Wgk1,
    const float* __restrict__ Wgk2, const float* __restrict__ bgk2,
    short* __restrict__ GK)
{
    const int row = blockIdx.x, tid = threadIdx.x;
    float p[16];
    #pragma unroll
    for (int j = 0; j < 16; j++) p[j] = 0.f;
    for (int d = tid; d < 1024; d += 256) {
        float xv = X[(size_t)row * 1024 + d];
        #pragma unroll
        for (int j = 0; j < 16; j++)
            p[j] = fmaf(xv, Wgk1[d * 16 + j], p[j]);
    }
    #pragma unroll
    for (int j = 0; j < 16; j++)
        for (int off = 32; off; off >>= 1) p[j] += __shfl_down(p[j], off);
    __shared__ float zp[4][16];
    __shared__ float z[16];
    const int lane = tid & 63, w = tid >> 6;
    if (lane == 0) {
        #pragma unroll
        for (int j = 0; j < 16; j++) zp[w][j] = p[j];
    }
    __syncthreads();
    if (tid < 16) z[tid] = zp[0][tid] + zp[1][tid] + zp[2][tid] + zp[3][tid];
    __syncthreads();
    for (int c = tid; c < 1024; c += 256) {
        float acc = bgk2[c];
        #pragma unroll
        for (int j = 0; j < 16; j++)
            acc = fmaf(z[j], Wgk2[j * 1024 + c], acc);
        float ls = fminf(acc, 0.f) - log1pf(expf(-fabsf(acc)));  // logsigmoid
        GK[(size_t)row * 1024 + c] = f2bf(ls * (1.f / 16.f));
    }
}

// ---------------- phase A: per-segment local scan (S starts at 0) ----------------
__global__ __launch_bounds__(256) void scan_local(
    const short* __restrict__ Q, const short* __restrict__ K,
    const short* __restrict__ V, const short* __restrict__ GK,
    float* __restrict__ O, float* __restrict__ SS, float* __restrict__ DSEG)
{
    const int seg = blockIdx.x;   // 0..7
    const int bh  = blockIdx.y;   // 0..15
    const int b = bh >> 3, h = bh & 7;
    const int tid = threadIdx.x;
    const int v = tid & 127, kh = tid >> 7;
    const int k0 = kh << 6;
    __shared__ float4 dkq[128];
    __shared__ float red[128];
    float s[64];
    #pragma unroll
    for (int i = 0; i < 64; i++) s[i] = 0.f;
    float gsum = 0.f;
    const size_t rowbase = (size_t)(b * 512 + seg * 64) * 1024 + h * 128;

    for (int t = 0; t < 64; t++) {
        const size_t base = rowbase + (size_t)t * 1024;
        if (tid < 128) {
            float gkv = bitf(GK[base + tid]);
            gsum += gkv;
            dkq[tid] = make_float4(expf(gkv), bitf(K[base + tid]), bitf(Q[base + tid]), 0.f);
        }
        float vv = bitf(V[base + v]);
        __syncthreads();             // barrier A: dkq ready
        float acc = 0.f;
        #pragma unroll
        for (int i = 0; i < 64; i++) {
            float4 d4 = dkq[k0 + i];
            s[i] = fmaf(s[i], d4.x, d4.y * vv);
            acc  = fmaf(d4.z, s[i], acc);
        }
        if (kh) red[v] = acc;
        __syncthreads();             // barrier B: red ready, dkq reads done
        if (!kh) O[base + v] = acc + red[v];
    }
    const size_t sbase = (size_t)(bh * 8 + seg) * 16384;
    #pragma unroll
    for (int i = 0; i < 64; i++) SS[sbase + (size_t)(k0 + i) * 128 + v] = s[i];
    if (tid < 128) DSEG[(bh * 8 + seg) * 128 + tid] = expf(gsum);
}

// ---------------- phase B: stitch segment states (parallel over elements) ----------------
__global__ __launch_bounds__(256) void stitch(
    float* __restrict__ SS, const float* __restrict__ DSEG)
{
    const int slice = blockIdx.x;   // 0..7 (slice of the 16384-element state)
    const int bh = blockIdx.y, tid = threadIdx.x;
    __shared__ float dloc[8][16];
    if (tid < 128)
        dloc[tid >> 4][tid & 15] = DSEG[(bh * 8 + (tid >> 4)) * 128 + slice * 16 + (tid & 15)];
    __syncthreads();
    float run[8];
    #pragma unroll
    for (int j = 0; j < 8; j++) run[j] = 0.f;
    for (int seg = 0; seg < 8; seg++) {
        const size_t base = (size_t)(bh * 8 + seg) * 16384 + slice * 2048;
        #pragma unroll
        for (int j = 0; j < 8; j++) {
            const int e = j * 256 + tid;
            float tmp = SS[base + e];
            SS[base + e] = run[j];                     // S_in for this segment
            run[j] = fmaf(run[j], dloc[seg][(e >> 7)], tmp);
        }
    }
}

// ---------------- phase C: o_t += (q_t * exp(Gcum_t)) @ S_in ----------------
__global__ __launch_bounds__(256) void correction(
    const short* __restrict__ Q, const short* __restrict__ GK,
    const float* __restrict__ SS, float* __restrict__ O)
{
    const int seg = blockIdx.x + 1;  // seg 0 has S_in = 0
    const int bh = blockIdx.y;
    const int b = bh >> 3, h = bh & 7;
    const int tid = threadIdx.x;
    __shared__ float qt[64][128];
    const size_t rowbase = (size_t)(b * 512 + seg * 64) * 1024 + h * 128;
    if (tid < 128) {
        float gsumc = 0.f;
        for (int t = 0; t < 64; t++) {
            const size_t base = rowbase + (size_t)t * 1024;
            gsumc += bitf(GK[base + tid]);
            qt[t][tid] = bitf(Q[base + tid]) * expf(gsumc);
        }
    }
    __syncthreads();
    const size_t sbase = (size_t)(bh * 8 + seg) * 16384;
    const int v = tid & 127, th = tid >> 7;  // th: half of t-range
    float acc[32];
    #pragma unroll
    for (int tt = 0; tt < 32; tt++) acc[tt] = 0.f;
    for (int k = 0; k < 128; k++) {
        float sv = SS[sbase + (size_t)k * 128 + v];
        #pragma unroll
        for (int tt = 0; tt < 32; tt++)
            acc[tt] = fmaf(qt[th * 32 + tt][k], sv, acc[tt]);
    }
    #pragma unroll
    for (int tt = 0; tt < 32; tt++) {
        const int t = th * 32 + tt;
        O[rowbase + (size_t)t * 1024 + v] += acc[tt];
    }
}

// ---------------- gated RMSNorm -> bf16 (into Obf) ----------------
__global__ __launch_bounds__(128) void gnorm(
    const float* __restrict__ O, const short* __restrict__ G,
    const float* __restrict__ gnw, short* __restrict__ NR)
{
    const int row = blockIdx.x;          // (b*T + t)*H + h
    const int bt = row >> 3, h = row & 7;
    const int v = threadIdx.x;
    const size_t idx = (size_t)bt * 1024 + h * 128 + v;
    float o = O[idx];
    float ss = o * o;
    for (int off = 32; off; off >>= 1) ss += __shfl_down(ss, off);
    __shared__ float w2[2];
    if ((v & 63) == 0) w2[v >> 6] = ss;
    __syncthreads();
    float ms = (w2[0] + w2[1]) * (1.f / 128.f);
    float r = rsqrtf(ms + 1e-5f);
    float g = bitf(G[idx]);
    float sg = g / (1.f + expf(-g));     // g * sigmoid(g)
    NR[idx] = f2bf(o * r * gnw[v] * sg);
}

extern "C" void kernel_launch(void* const* d_in, const int* in_sizes, int n_in,
                              void* d_out, int out_size, void* d_ws, size_t ws_size,
                              hipStream_t stream)
{
    const float* X    = (const float*)d_in[0];
    const float* Wq   = (const float*)d_in[1];
    const float* Wk   = (const float*)d_in[2];
    const float* Wv   = (const float*)d_in[3];
    const float* Wg   = (const float*)d_in[4];
    const float* Wgk1 = (const float*)d_in[5];
    const float* Wgk2 = (const float*)d_in[6];
    const float* bgk2 = (const float*)d_in[7];
    const float* gnw  = (const float*)d_in[8];
    const float* Wo   = (const float*)d_in[9];
    float* OUT = (float*)d_out;   // reference output is float32

    // workspace layout (32.1 MB):
    short* QKVG = (short*)d_ws;               // 4 x 1M bf16 (Q,K,V,G)     [8 MB]
    short* GK   = QKVG + (4u << 20);          // 1M bf16                   [2 MB]
    float* Ob   = (float*)(GK + (1u << 20));  // 1M f32                    [4 MB]
    float* SS   = Ob + (1u << 20);            // 2M f32                    [8 MB]
    float* DS   = SS + (2u << 20);            // 16K f32                   [64 KB]
    short* WT   = (short*)(DS + 16384);       // 5 x 1M bf16 (W^T)         [10 MB]
    short* Obf  = QKVG;                       // alias Q (dead after correction)

    cast_wt<<<dim3(32, 32, 5), 256, 0, stream>>>(Wq, Wk, Wv, Wg, Wo, WT);
    proj_gemm<<<dim3(8, 8, 4), 256, 0, stream>>>(X, WT, QKVG);
    gk_proj<<<dim3(BT), 256, 0, stream>>>(X, Wgk1, Wgk2, bgk2, GK);
    scan_local<<<dim3(NSEG, NBH), 256, 0, stream>>>(
        QKVG, QKVG + (1u << 20), QKVG + (2u << 20), GK, Ob, SS, DS);
    stitch<<<dim3(8, NBH), 256, 0, stream>>>(SS, DS);
    correction<<<dim3(NSEG - 1, NBH), 256, 0, stream>>>(QKVG, GK, SS, Ob);
    gnorm<<<dim3(BT * NH), 128, 0, stream>>>(Ob, QKVG + (3u << 20), gnw, Obf);
    wo_gemm<<<dim3(8, 8), 256, 0, stream>>>(Obf, WT + (4u << 20), OUT);
}

// Round 6
// 264.226 us; speedup vs baseline: 1.6898x; 1.2815x over previous
//
#include <hip/hip_runtime.h>
#include <hip/hip_bf16.h>
#include <math.h>

#define BT     1024   // B*T
#define NH     8
#define SEGLEN 32
#define NSEG   16     // segments per sequence (T=512)
#define NBH    16     // B*H

typedef __attribute__((ext_vector_type(8))) short short8;
typedef __attribute__((ext_vector_type(4))) float f32x4;

__device__ __forceinline__ float bitf(short u) {
    union { float f; unsigned i; } x; x.i = ((unsigned)(unsigned short)u) << 16; return x.f;
}
__device__ __forceinline__ short f2bf(float f) {   // RNE f32->bf16
    union { float f; unsigned u; } x; x.f = f;
    unsigned r = x.u + 0x7FFF + ((x.u >> 16) & 1);
    return (short)(r >> 16);
}

// ---------------- transpose+cast: W[k][n] f32 -> WT[n][k] bf16, 5 weights ----------------
__global__ __launch_bounds__(256) void cast_wt(
    const float* __restrict__ Wq, const float* __restrict__ Wk,
    const float* __restrict__ Wv, const float* __restrict__ Wg,
    const float* __restrict__ Wo, short* __restrict__ WT)
{
    const int z = blockIdx.z;
    const float* W = (z == 0) ? Wq : (z == 1) ? Wk : (z == 2) ? Wv : (z == 3) ? Wg : Wo;
    short* T = WT + (size_t)z * (1u << 20);
    __shared__ float tile[32][33];
    const int tid = threadIdx.x;
    const int k0 = blockIdx.y * 32, n0 = blockIdx.x * 32;
    const int row = tid >> 3, c4 = (tid & 7) << 2;
    float4 f = *(const float4*)(W + (size_t)(k0 + row) * 1024 + n0 + c4);
    tile[row][c4 + 0] = f.x; tile[row][c4 + 1] = f.y;
    tile[row][c4 + 2] = f.z; tile[row][c4 + 3] = f.w;
    __syncthreads();
    short* o = T + (size_t)(n0 + row) * 1024 + k0 + c4;
    o[0] = f2bf(tile[c4 + 0][row]); o[1] = f2bf(tile[c4 + 1][row]);
    o[2] = f2bf(tile[c4 + 2][row]); o[3] = f2bf(tile[c4 + 3][row]);
}

// ---------------- MFMA GEMM: X(f32)@W -> bf16 out, fused over 4 weights ----------------
__global__ __launch_bounds__(256) void proj_gemm(
    const float* __restrict__ X, const short* __restrict__ WT,
    short* __restrict__ QKVG)
{
    const int z = blockIdx.z;
    const float scale = (z == 0) ? 0.08838834764831845f : 1.0f;  // HK^-0.5 on q
    short* C = QKVG + (size_t)z * (1u << 20);
    const short* B = WT + (size_t)z * (1u << 20);

    __shared__ __align__(16) short As[8 * 128 * 8];  // 16 KB
    __shared__ __align__(16) short Bs[8 * 128 * 8];  // 16 KB
    const int tid = threadIdx.x;
    const int wave = tid >> 6, lane = tid & 63;
    const int wm = (wave >> 1) * 64, wn = (wave & 1) * 64;
    const int m15 = lane & 15, q = lane >> 4;
    const int m0 = blockIdx.y * 128, n0 = blockIdx.x * 128;
    const int r = tid & 127, kh = tid >> 7;

    f32x4 acc[4][4];
    #pragma unroll
    for (int i = 0; i < 4; i++)
        #pragma unroll
        for (int j = 0; j < 4; j++)
            acc[i][j] = (f32x4){0.f, 0.f, 0.f, 0.f};

    for (int kb0 = 0; kb0 < 1024; kb0 += 64) {
        __syncthreads();
        {
            const float4* src = (const float4*)(X + (size_t)(m0 + r) * 1024 + kb0 + kh * 32);
            #pragma unroll
            for (int jj = 0; jj < 4; jj++) {
                float4 fa = src[2 * jj], fb = src[2 * jj + 1];
                short8 v;
                v[0] = f2bf(fa.x); v[1] = f2bf(fa.y); v[2] = f2bf(fa.z); v[3] = f2bf(fa.w);
                v[4] = f2bf(fb.x); v[5] = f2bf(fb.y); v[6] = f2bf(fb.z); v[7] = f2bf(fb.w);
                *(short8*)&As[(((kh << 2) + jj) * 128 + r) * 8] = v;
            }
        }
        {
            const short8* src = (const short8*)(B + (size_t)(n0 + r) * 1024 + kb0 + kh * 32);
            #pragma unroll
            for (int jj = 0; jj < 4; jj++)
                *(short8*)&Bs[(((kh << 2) + jj) * 128 + r) * 8] = src[jj];
        }
        __syncthreads();
        #pragma unroll
        for (int s = 0; s < 2; s++) {
            short8 af[4], bf[4];
            const int kq = ((s << 2) + q) * 128;
            #pragma unroll
            for (int i = 0; i < 4; i++)
                af[i] = *(const short8*)&As[(kq + wm + i * 16 + m15) * 8];
            #pragma unroll
            for (int j = 0; j < 4; j++)
                bf[j] = *(const short8*)&Bs[(kq + wn + j * 16 + m15) * 8];
            #pragma unroll
            for (int i = 0; i < 4; i++)
                #pragma unroll
                for (int j = 0; j < 4; j++)
                    acc[i][j] = __builtin_amdgcn_mfma_f32_16x16x32_bf16(af[i], bf[j], acc[i][j], 0, 0, 0);
        }
    }
    #pragma unroll
    for (int i = 0; i < 4; i++)
        #pragma unroll
        for (int j = 0; j < 4; j++)
            #pragma unroll
            for (int rr = 0; rr < 4; rr++)
                C[(size_t)(m0 + wm + i * 16 + q * 4 + rr) * 1024 + n0 + wn + j * 16 + m15] =
                    f2bf(acc[i][j][rr] * scale);
}

// ---------------- MFMA GEMM: Obf(bf16)@WoT -> out f32 ----------------
__global__ __launch_bounds__(256) void wo_gemm(
    const short* __restrict__ A, const short* __restrict__ B, float* __restrict__ C)
{
    __shared__ __align__(16) short As[8 * 128 * 8];
    __shared__ __align__(16) short Bs[8 * 128 * 8];
    const int tid = threadIdx.x;
    const int wave = tid >> 6, lane = tid & 63;
    const int wm = (wave >> 1) * 64, wn = (wave & 1) * 64;
    const int m15 = lane & 15, q = lane >> 4;
    const int m0 = blockIdx.y * 128, n0 = blockIdx.x * 128;
    const int r = tid & 127, kh = tid >> 7;

    f32x4 acc[4][4];
    #pragma unroll
    for (int i = 0; i < 4; i++)
        #pragma unroll
        for (int j = 0; j < 4; j++)
            acc[i][j] = (f32x4){0.f, 0.f, 0.f, 0.f};

    for (int kb0 = 0; kb0 < 1024; kb0 += 64) {
        __syncthreads();
        {
            const short8* src = (const short8*)(A + (size_t)(m0 + r) * 1024 + kb0 + kh * 32);
            #pragma unroll
            for (int jj = 0; jj < 4; jj++)
                *(short8*)&As[(((kh << 2) + jj) * 128 + r) * 8] = src[jj];
        }
        {
            const short8* src = (const short8*)(B + (size_t)(n0 + r) * 1024 + kb0 + kh * 32);
            #pragma unroll
            for (int jj = 0; jj < 4; jj++)
                *(short8*)&Bs[(((kh << 2) + jj) * 128 + r) * 8] = src[jj];
        }
        __syncthreads();
        #pragma unroll
        for (int s = 0; s < 2; s++) {
            short8 af[4], bf[4];
            const int kq = ((s << 2) + q) * 128;
            #pragma unroll
            for (int i = 0; i < 4; i++)
                af[i] = *(const short8*)&As[(kq + wm + i * 16 + m15) * 8];
            #pragma unroll
            for (int j = 0; j < 4; j++)
                bf[j] = *(const short8*)&Bs[(kq + wn + j * 16 + m15) * 8];
            #pragma unroll
            for (int i = 0; i < 4; i++)
                #pragma unroll
                for (int j = 0; j < 4; j++)
                    acc[i][j] = __builtin_amdgcn_mfma_f32_16x16x32_bf16(af[i], bf[j], acc[i][j], 0, 0, 0);
        }
    }
    #pragma unroll
    for (int i = 0; i < 4; i++)
        #pragma unroll
        for (int j = 0; j < 4; j++)
            #pragma unroll
            for (int rr = 0; rr < 4; rr++)
                C[(size_t)(m0 + wm + i * 16 + q * 4 + rr) * 1024 + n0 + wn + j * 16 + m15] =
                    acc[i][j][rr];
}

// ---------------- low-rank gate: gk = logsigmoid(x@Wgk1@Wgk2 + b)/16 -> bf16 ----------------
__global__ __launch_bounds__(256) void gk_proj(
    const float* __restrict__ X, const float* __restrict__ Wgk1,
    const float* __restrict__ Wgk2, const float* __restrict__ bgk2,
    short* __restrict__ GK)
{
    const int row = blockIdx.x, tid = threadIdx.x;
    float p[16];
    #pragma unroll
    for (int j = 0; j < 16; j++) p[j] = 0.f;
    for (int d = tid; d < 1024; d += 256) {
        float xv = X[(size_t)row * 1024 + d];
        #pragma unroll
        for (int j = 0; j < 16; j++)
            p[j] = fmaf(xv, Wgk1[d * 16 + j], p[j]);
    }
    #pragma unroll
    for (int j = 0; j < 16; j++)
        for (int off = 32; off; off >>= 1) p[j] += __shfl_down(p[j], off);
    __shared__ float zp[4][16];
    __shared__ float z[16];
    const int lane = tid & 63, w = tid >> 6;
    if (lane == 0) {
        #pragma unroll
        for (int j = 0; j < 16; j++) zp[w][j] = p[j];
    }
    __syncthreads();
    if (tid < 16) z[tid] = zp[0][tid] + zp[1][tid] + zp[2][tid] + zp[3][tid];
    __syncthreads();
    for (int c = tid; c < 1024; c += 256) {
        float acc = bgk2[c];
        #pragma unroll
        for (int j = 0; j < 16; j++)
            acc = fmaf(z[j], Wgk2[j * 1024 + c], acc);
        float ls = fminf(acc, 0.f) - log1pf(expf(-fabsf(acc)));  // logsigmoid
        GK[(size_t)row * 1024 + c] = f2bf(ls * (1.f / 16.f));
    }
}

// ---------------- phase A: per-segment local scan, software-pipelined ----------------
// v/kh remap keeps both k-halves of a v in the SAME wave -> shfl_xor reduction,
// double-buffered dkq -> single barrier per step.
__global__ __launch_bounds__(256) void scan_local(
    const short* __restrict__ Q, const short* __restrict__ K,
    const short* __restrict__ V, const short* __restrict__ GK,
    float* __restrict__ O, short* __restrict__ SS, float* __restrict__ DSEG)
{
    const int seg = blockIdx.x;   // 0..15
    const int bh  = blockIdx.y;   // 0..15
    const int b = bh >> 3, h = bh & 7;
    const int tid = threadIdx.x;
    const int wave = tid >> 6, lane = tid & 63;
    const int kh = lane >> 5;                 // k-half within wave
    const int v = wave * 32 + (lane & 31);    // value channel 0..127
    const int k0 = kh << 6;
    __shared__ float4 dkq[2][128];
    float s[64];
    #pragma unroll
    for (int i = 0; i < 64; i++) s[i] = 0.f;
    float gsum = 0.f;
    const size_t rowbase = (size_t)(b * 512 + seg * SEGLEN) * 1024 + h * 128;

    // prologue loads (step 0)
    float gk_c = 0.f, k_c = 0.f, q_c = 0.f, v_c;
    if (tid < 128) {
        gk_c = bitf(GK[rowbase + tid]);
        k_c  = bitf(K[rowbase + tid]);
        q_c  = bitf(Q[rowbase + tid]);
    }
    v_c = bitf(V[rowbase + v]);

    for (int t = 0; t < SEGLEN; t++) {
        const size_t base  = rowbase + (size_t)t * 1024;
        const size_t nbase = rowbase + (size_t)(t < SEGLEN - 1 ? t + 1 : t) * 1024;
        // prefetch next step (overlaps with this step's compute)
        float gk_n = 0.f, k_n = 0.f, q_n = 0.f, v_n;
        if (tid < 128) {
            gk_n = bitf(GK[nbase + tid]);
            k_n  = bitf(K[nbase + tid]);
            q_n  = bitf(Q[nbase + tid]);
        }
        v_n = bitf(V[nbase + v]);

        const int p = t & 1;
        if (tid < 128) {
            gsum += gk_c;
            dkq[p][tid] = make_float4(expf(gk_c), k_c, q_c, 0.f);
        }
        __syncthreads();             // dkq[p] ready; dkq[1-p] readers from t-1 already past
        float acc = 0.f;
        #pragma unroll
        for (int i = 0; i < 64; i++) {
            float4 d4 = dkq[p][k0 + i];
            s[i] = fmaf(s[i], d4.x, d4.y * v_c);
            acc  = fmaf(d4.z, s[i], acc);
        }
        acc += __shfl_xor(acc, 32);  // combine the two k-halves (same wave)
        if (kh == 0) O[base + v] = acc;
        gk_c = gk_n; k_c = k_n; q_c = q_n; v_c = v_n;
    }
    const size_t sbase = (size_t)(bh * NSEG + seg) * 16384;
    #pragma unroll
    for (int i = 0; i < 64; i++) SS[sbase + (size_t)(k0 + i) * 128 + v] = f2bf(s[i]);
    if (tid < 128) DSEG[(bh * NSEG + seg) * 128 + tid] = expf(gsum);
}

// ---------------- phase B: stitch segment states (parallel over elements) ----------------
__global__ __launch_bounds__(256) void stitch(
    short* __restrict__ SS, const float* __restrict__ DSEG)
{
    const int slice = blockIdx.x;   // 0..7 (slice of the 16384-element state)
    const int bh = blockIdx.y, tid = threadIdx.x;
    __shared__ float dloc[NSEG][16];
    dloc[tid >> 4][tid & 15] = DSEG[(bh * NSEG + (tid >> 4)) * 128 + slice * 16 + (tid & 15)];
    __syncthreads();
    float run[8];
    #pragma unroll
    for (int j = 0; j < 8; j++) run[j] = 0.f;
    for (int seg = 0; seg < NSEG; seg++) {
        const size_t base = (size_t)(bh * NSEG + seg) * 16384 + slice * 2048;
        #pragma unroll
        for (int j = 0; j < 8; j++) {
            const int e = j * 256 + tid;
            float tmp = bitf(SS[base + e]);
            SS[base + e] = f2bf(run[j]);               // S_in for this segment
            run[j] = fmaf(run[j], dloc[seg][(e >> 7)], tmp);
        }
    }
}

// ---------------- phase C: o_t += (q_t * exp(Gcum_t)) @ S_in ----------------
__global__ __launch_bounds__(256) void correction(
    const short* __restrict__ Q, const short* __restrict__ GK,
    const short* __restrict__ SS, float* __restrict__ O)
{
    const int seg = blockIdx.x + 1;  // seg 0 has S_in = 0
    const int bh = blockIdx.y;
    const int b = bh >> 3, h = bh & 7;
    const int tid = threadIdx.x;
    __shared__ float qt[SEGLEN][128];
    const size_t rowbase = (size_t)(b * 512 + seg * SEGLEN) * 1024 + h * 128;
    if (tid < 128) {
        float gsumc = 0.f;
        for (int t = 0; t < SEGLEN; t++) {
            const size_t base = rowbase + (size_t)t * 1024;
            gsumc += bitf(GK[base + tid]);
            qt[t][tid] = bitf(Q[base + tid]) * expf(gsumc);
        }
    }
    __syncthreads();
    const size_t sbase = (size_t)(bh * NSEG + seg) * 16384;
    const int v = tid & 127, th = tid >> 7;  // th: half of t-range
    float acc[SEGLEN / 2];
    #pragma unroll
    for (int tt = 0; tt < SEGLEN / 2; tt++) acc[tt] = 0.f;
    for (int k = 0; k < 128; k++) {
        float sv = bitf(SS[sbase + (size_t)k * 128 + v]);
        #pragma unroll
        for (int tt = 0; tt < SEGLEN / 2; tt++)
            acc[tt] = fmaf(qt[th * (SEGLEN / 2) + tt][k], sv, acc[tt]);
    }
    #pragma unroll
    for (int tt = 0; tt < SEGLEN / 2; tt++) {
        const int t = th * (SEGLEN / 2) + tt;
        O[rowbase + (size_t)t * 1024 + v] += acc[tt];
    }
}

// ---------------- gated RMSNorm -> bf16 (into Obf) ----------------
__global__ __launch_bounds__(128) void gnorm(
    const float* __restrict__ O, const short* __restrict__ G,
    const float* __restrict__ gnw, short* __restrict__ NR)
{
    const int row = blockIdx.x;          // (b*T + t)*H + h
    const int bt = row >> 3, h = row & 7;
    const int v = threadIdx.x;
    const size_t idx = (size_t)bt * 1024 + h * 128 + v;
    float o = O[idx];
    float ss = o * o;
    for (int off = 32; off; off >>= 1) ss += __shfl_down(ss, off);
    __shared__ float w2[2];
    if ((v & 63) == 0) w2[v >> 6] = ss;
    __syncthreads();
    float ms = (w2[0] + w2[1]) * (1.f / 128.f);
    float r = rsqrtf(ms + 1e-5f);
    float g = bitf(G[idx]);
    float sg = g / (1.f + expf(-g));     // g * sigmoid(g)
    NR[idx] = f2bf(o * r * gnw[v] * sg);
}

extern "C" void kernel_launch(void* const* d_in, const int* in_sizes, int n_in,
                              void* d_out, int out_size, void* d_ws, size_t ws_size,
                              hipStream_t stream)
{
    const float* X    = (const float*)d_in[0];
    const float* Wq   = (const float*)d_in[1];
    const float* Wk   = (const float*)d_in[2];
    const float* Wv   = (const float*)d_in[3];
    const float* Wg   = (const float*)d_in[4];
    const float* Wgk1 = (const float*)d_in[5];
    const float* Wgk2 = (const float*)d_in[6];
    const float* bgk2 = (const float*)d_in[7];
    const float* gnw  = (const float*)d_in[8];
    const float* Wo   = (const float*)d_in[9];
    float* OUT = (float*)d_out;   // reference output is float32

    // workspace layout (~32.1 MiB):
    short* QKVG = (short*)d_ws;               // 4 x 1M bf16 (Q,K,V,G)     [8 MiB]
    short* GK   = QKVG + (4u << 20);          // 1M bf16                   [2 MiB]
    float* Ob   = (float*)(GK + (1u << 20));  // 1M f32                    [4 MiB]
    short* SS   = (short*)(Ob + (1u << 20));  // 16bh x 16seg x 128x128 bf16 [8 MiB]
    float* DS   = (float*)(SS + (4u << 20));  // 32K f32                   [128 KiB]
    short* WT   = (short*)(DS + 32768);       // 5 x 1M bf16 (W^T)         [10 MiB]
    short* Obf  = QKVG;                       // alias Q (dead after correction)

    cast_wt<<<dim3(32, 32, 5), 256, 0, stream>>>(Wq, Wk, Wv, Wg, Wo, WT);
    proj_gemm<<<dim3(8, 8, 4), 256, 0, stream>>>(X, WT, QKVG);
    gk_proj<<<dim3(BT), 256, 0, stream>>>(X, Wgk1, Wgk2, bgk2, GK);
    scan_local<<<dim3(NSEG, NBH), 256, 0, stream>>>(
        QKVG, QKVG + (1u << 20), QKVG + (2u << 20), GK, Ob, SS, DS);
    stitch<<<dim3(8, NBH), 256, 0, stream>>>(SS, DS);
    correction<<<dim3(NSEG - 1, NBH), 256, 0, stream>>>(QKVG, GK, SS, Ob);
    gnorm<<<dim3(BT * NH), 128, 0, stream>>>(Ob, QKVG + (3u << 20), gnw, Obf);
    wo_gemm<<<dim3(8, 8), 256, 0, stream>>>(Obf, WT + (4u << 20), OUT);
}

// Round 7
// 204.464 us; speedup vs baseline: 2.1837x; 1.2923x over previous
//
#include <hip/hip_runtime.h>
#include <hip/hip_bf16.h>
#include <math.h>

#define BT     1024   // B*T
#define NH     8
#define SEGLEN 32
#define NSEG   16     // segments per sequence (T=512)
#define NBH    16     // B*H
#define QKS    136    // Qt/Kt LDS row stride (shorts) — breaks 16-way frag-read conflict
#define VTS    40     // VT/KhT LDS row stride
#define AMS    40     // Am LDS row stride

typedef __attribute__((ext_vector_type(8))) short short8;
typedef __attribute__((ext_vector_type(4))) short sh4;
typedef __attribute__((ext_vector_type(4))) float f32x4;

__device__ __forceinline__ float bitf(short u) {
    union { float f; unsigned i; } x; x.i = ((unsigned)(unsigned short)u) << 16; return x.f;
}
__device__ __forceinline__ short f2bf(float f) {   // RNE f32->bf16
    union { float f; unsigned u; } x; x.f = f;
    unsigned r = x.u + 0x7FFF + ((x.u >> 16) & 1);
    return (short)(r >> 16);
}

// ---------------- transpose+cast: W[k][n] f32 -> WT[n][k] bf16, 5 weights ----------------
__global__ __launch_bounds__(256) void cast_wt(
    const float* __restrict__ Wq, const float* __restrict__ Wk,
    const float* __restrict__ Wv, const float* __restrict__ Wg,
    const float* __restrict__ Wo, short* __restrict__ WT)
{
    const int z = blockIdx.z;
    const float* W = (z == 0) ? Wq : (z == 1) ? Wk : (z == 2) ? Wv : (z == 3) ? Wg : Wo;
    short* T = WT + (size_t)z * (1u << 20);
    __shared__ float tile[32][33];
    const int tid = threadIdx.x;
    const int k0 = blockIdx.y * 32, n0 = blockIdx.x * 32;
    const int row = tid >> 3, c4 = (tid & 7) << 2;
    float4 f = *(const float4*)(W + (size_t)(k0 + row) * 1024 + n0 + c4);
    tile[row][c4 + 0] = f.x; tile[row][c4 + 1] = f.y;
    tile[row][c4 + 2] = f.z; tile[row][c4 + 3] = f.w;
    __syncthreads();
    short* o = T + (size_t)(n0 + row) * 1024 + k0 + c4;
    o[0] = f2bf(tile[c4 + 0][row]); o[1] = f2bf(tile[c4 + 1][row]);
    o[2] = f2bf(tile[c4 + 2][row]); o[3] = f2bf(tile[c4 + 3][row]);
}

// ---------------- MFMA GEMM: X(f32)@W -> bf16 out, fused over 4 weights ----------------
__global__ __launch_bounds__(256) void proj_gemm(
    const float* __restrict__ X, const short* __restrict__ WT,
    short* __restrict__ QKVG)
{
    const int z = blockIdx.z;
    const float scale = (z == 0) ? 0.08838834764831845f : 1.0f;  // HK^-0.5 on q
    short* C = QKVG + (size_t)z * (1u << 20);
    const short* B = WT + (size_t)z * (1u << 20);

    __shared__ __align__(16) short As[8 * 128 * 8];  // 16 KB
    __shared__ __align__(16) short Bs[8 * 128 * 8];  // 16 KB
    const int tid = threadIdx.x;
    const int wave = tid >> 6, lane = tid & 63;
    const int wm = (wave >> 1) * 64, wn = (wave & 1) * 64;
    const int m15 = lane & 15, q = lane >> 4;
    const int m0 = blockIdx.y * 128, n0 = blockIdx.x * 128;
    const int r = tid & 127, kh = tid >> 7;

    f32x4 acc[4][4];
    #pragma unroll
    for (int i = 0; i < 4; i++)
        #pragma unroll
        for (int j = 0; j < 4; j++)
            acc[i][j] = (f32x4){0.f, 0.f, 0.f, 0.f};

    for (int kb0 = 0; kb0 < 1024; kb0 += 64) {
        __syncthreads();
        {
            const float4* src = (const float4*)(X + (size_t)(m0 + r) * 1024 + kb0 + kh * 32);
            #pragma unroll
            for (int jj = 0; jj < 4; jj++) {
                float4 fa = src[2 * jj], fb = src[2 * jj + 1];
                short8 v;
                v[0] = f2bf(fa.x); v[1] = f2bf(fa.y); v[2] = f2bf(fa.z); v[3] = f2bf(fa.w);
                v[4] = f2bf(fb.x); v[5] = f2bf(fb.y); v[6] = f2bf(fb.z); v[7] = f2bf(fb.w);
                *(short8*)&As[(((kh << 2) + jj) * 128 + r) * 8] = v;
            }
        }
        {
            const short8* src = (const short8*)(B + (size_t)(n0 + r) * 1024 + kb0 + kh * 32);
            #pragma unroll
            for (int jj = 0; jj < 4; jj++)
                *(short8*)&Bs[(((kh << 2) + jj) * 128 + r) * 8] = src[jj];
        }
        __syncthreads();
        #pragma unroll
        for (int s = 0; s < 2; s++) {
            short8 af[4], bf[4];
            const int kq = ((s << 2) + q) * 128;
            #pragma unroll
            for (int i = 0; i < 4; i++)
                af[i] = *(const short8*)&As[(kq + wm + i * 16 + m15) * 8];
            #pragma unroll
            for (int j = 0; j < 4; j++)
                bf[j] = *(const short8*)&Bs[(kq + wn + j * 16 + m15) * 8];
            #pragma unroll
            for (int i = 0; i < 4; i++)
                #pragma unroll
                for (int j = 0; j < 4; j++)
                    acc[i][j] = __builtin_amdgcn_mfma_f32_16x16x32_bf16(af[i], bf[j], acc[i][j], 0, 0, 0);
        }
    }
    #pragma unroll
    for (int i = 0; i < 4; i++)
        #pragma unroll
        for (int j = 0; j < 4; j++)
            #pragma unroll
            for (int rr = 0; rr < 4; rr++)
                C[(size_t)(m0 + wm + i * 16 + q * 4 + rr) * 1024 + n0 + wn + j * 16 + m15] =
                    f2bf(acc[i][j][rr] * scale);
}

// ---------------- MFMA GEMM: Obf(bf16)@WoT -> out f32 ----------------
__global__ __launch_bounds__(256) void wo_gemm(
    const short* __restrict__ A, const short* __restrict__ B, float* __restrict__ C)
{
    __shared__ __align__(16) short As[8 * 128 * 8];
    __shared__ __align__(16) short Bs[8 * 128 * 8];
    const int tid = threadIdx.x;
    const int wave = tid >> 6, lane = tid & 63;
    const int wm = (wave >> 1) * 64, wn = (wave & 1) * 64;
    const int m15 = lane & 15, q = lane >> 4;
    const int m0 = blockIdx.y * 128, n0 = blockIdx.x * 128;
    const int r = tid & 127, kh = tid >> 7;

    f32x4 acc[4][4];
    #pragma unroll
    for (int i = 0; i < 4; i++)
        #pragma unroll
        for (int j = 0; j < 4; j++)
            acc[i][j] = (f32x4){0.f, 0.f, 0.f, 0.f};

    for (int kb0 = 0; kb0 < 1024; kb0 += 64) {
        __syncthreads();
        {
            const short8* src = (const short8*)(A + (size_t)(m0 + r) * 1024 + kb0 + kh * 32);
            #pragma unroll
            for (int jj = 0; jj < 4; jj++)
                *(short8*)&As[(((kh << 2) + jj) * 128 + r) * 8] = src[jj];
        }
        {
            const short8* src = (const short8*)(B + (size_t)(n0 + r) * 1024 + kb0 + kh * 32);
            #pragma unroll
            for (int jj = 0; jj < 4; jj++)
                *(short8*)&Bs[(((kh << 2) + jj) * 128 + r) * 8] = src[jj];
        }
        __syncthreads();
        #pragma unroll
        for (int s = 0; s < 2; s++) {
            short8 af[4], bf[4];
            const int kq = ((s << 2) + q) * 128;
            #pragma unroll
            for (int i = 0; i < 4; i++)
                af[i] = *(const short8*)&As[(kq + wm + i * 16 + m15) * 8];
            #pragma unroll
            for (int j = 0; j < 4; j++)
                bf[j] = *(const short8*)&Bs[(kq + wn + j * 16 + m15) * 8];
            #pragma unroll
            for (int i = 0; i < 4; i++)
                #pragma unroll
                for (int j = 0; j < 4; j++)
                    acc[i][j] = __builtin_amdgcn_mfma_f32_16x16x32_bf16(af[i], bf[j], acc[i][j], 0, 0, 0);
        }
    }
    #pragma unroll
    for (int i = 0; i < 4; i++)
        #pragma unroll
        for (int j = 0; j < 4; j++)
            #pragma unroll
            for (int rr = 0; rr < 4; rr++)
                C[(size_t)(m0 + wm + i * 16 + q * 4 + rr) * 1024 + n0 + wn + j * 16 + m15] =
                    acc[i][j][rr];
}

// ---------------- low-rank gate: gk = logsigmoid(x@Wgk1@Wgk2 + b)/16 -> bf16 ----------------
__global__ __launch_bounds__(256) void gk_proj(
    const float* __restrict__ X, const float* __restrict__ Wgk1,
    const float* __restrict__ Wgk2, const float* __restrict__ bgk2,
    short* __restrict__ GK)
{
    const int row = blockIdx.x, tid = threadIdx.x;
    float p[16];
    #pragma unroll
    for (int j = 0; j < 16; j++) p[j] = 0.f;
    for (int d = tid; d < 1024; d += 256) {
        float xv = X[(size_t)row * 1024 + d];
        #pragma unroll
        for (int j = 0; j < 16; j++)
            p[j] = fmaf(xv, Wgk1[d * 16 + j], p[j]);
    }
    #pragma unroll
    for (int j = 0; j < 16; j++)
        for (int off = 32; off; off >>= 1) p[j] += __shfl_down(p[j], off);
    __shared__ float zp[4][16];
    __shared__ float z[16];
    const int lane = tid & 63, w = tid >> 6;
    if (lane == 0) {
        #pragma unroll
        for (int j = 0; j < 16; j++) zp[w][j] = p[j];
    }
    __syncthreads();
    if (tid < 16) z[tid] = zp[0][tid] + zp[1][tid] + zp[2][tid] + zp[3][tid];
    __syncthreads();
    for (int c = tid; c < 1024; c += 256) {
        float acc = bgk2[c];
        #pragma unroll
        for (int j = 0; j < 16; j++)
            acc = fmaf(z[j], Wgk2[j * 1024 + c], acc);
        float ls = fminf(acc, 0.f) - log1pf(expf(-fabsf(acc)));  // logsigmoid
        GK[(size_t)row * 1024 + c] = f2bf(ls * (1.f / 16.f));
    }
}

// ---------------- phase A: chunked scan via MFMA ----------------
// Per (bh, seg): Gc = cumsum(gk); Qt = q*exp(Gc); Kt = k*exp(-Gc); Kh = k*exp(Gend-Gc).
// A = mask(Qt@Kt^T); O_intra = A@V; S_local = Kh^T@V. Qt also stored to global
// (aliases the dead GK buffer) for the correction kernel.
__global__ __launch_bounds__(256) void scan_chunk(
    const short* __restrict__ Q, const short* __restrict__ K,
    const short* __restrict__ V, short* GKQT,
    float* __restrict__ O, short* __restrict__ SS, float* __restrict__ DSEG)
{
    const int seg = blockIdx.x;   // 0..15
    const int bh  = blockIdx.y;   // 0..15
    const int b = bh >> 3, h = bh & 7;
    const int tid = threadIdx.x;
    const size_t rowbase = (size_t)(b * 512 + seg * SEGLEN) * 1024 + h * 128;

    __shared__ __align__(16) short Qt[32 * QKS];
    __shared__ __align__(16) short Kt[32 * QKS];
    __shared__ __align__(16) short Vs[32 * 128];
    __shared__ __align__(16) short VT[128 * VTS];
    __shared__ __align__(16) short KhT[128 * VTS];
    __shared__ __align__(16) short Am[32 * AMS];

    if (tid < 128) {
        const int ch = tid;
        float gsum = 0.f;
        float ktf[32];
        #pragma unroll
        for (int t = 0; t < 32; t++) {
            const size_t a = rowbase + (size_t)t * 1024 + ch;
            float g  = bitf(GKQT[a]);
            float kv = bitf(K[a]);
            float qv = bitf(Q[a]);
            gsum += g;
            float eg  = expf(gsum);
            float emg = expf(-gsum);
            short qts = f2bf(qv * eg);
            Qt[t * QKS + ch] = qts;
            GKQT[a] = qts;                       // write Q~ over GK (read-before-write per addr)
            float ktv = kv * emg;
            Kt[t * QKS + ch] = f2bf(ktv);
            ktf[t] = ktv;
        }
        float eGend = expf(gsum);
        DSEG[(bh * NSEG + seg) * 128 + ch] = eGend;
        #pragma unroll
        for (int t4 = 0; t4 < 8; t4++) {
            sh4 p;
            p[0] = f2bf(ktf[4 * t4 + 0] * eGend);
            p[1] = f2bf(ktf[4 * t4 + 1] * eGend);
            p[2] = f2bf(ktf[4 * t4 + 2] * eGend);
            p[3] = f2bf(ktf[4 * t4 + 3] * eGend);
            *(sh4*)&KhT[ch * VTS + 4 * t4] = p;
        }
    } else {
        const int u = tid - 128;
        #pragma unroll
        for (int i = 0; i < 4; i++) {
            const int idx = u + i * 128;          // short8 index, 512 total
            const int t = idx >> 4, c = idx & 15;
            short8 vv = *(const short8*)&V[rowbase + (size_t)t * 1024 + c * 8];
            *(short8*)&Vs[t * 128 + c * 8] = vv;
        }
    }
    __syncthreads();
    // V transpose: VT[ch][t]
    {
        const int ch = tid >> 1, t0 = (tid & 1) * 16;
        #pragma unroll
        for (int j = 0; j < 4; j++) {
            sh4 p;
            p[0] = Vs[(t0 + 4 * j + 0) * 128 + ch];
            p[1] = Vs[(t0 + 4 * j + 1) * 128 + ch];
            p[2] = Vs[(t0 + 4 * j + 2) * 128 + ch];
            p[3] = Vs[(t0 + 4 * j + 3) * 128 + ch];
            *(sh4*)&VT[ch * VTS + t0 + 4 * j] = p;
        }
    }
    __syncthreads();

    const int wave = tid >> 6, lane = tid & 63;
    const int m15 = lane & 15, q = lane >> 4;

    // GEMM1: A = Qt(32x128) @ Kt^T, causal mask, -> Am bf16
    {
        const int mi = wave >> 1, ni = wave & 1;
        f32x4 a1 = (f32x4){0.f, 0.f, 0.f, 0.f};
        #pragma unroll
        for (int kc = 0; kc < 4; kc++) {
            short8 af = *(const short8*)&Qt[(mi * 16 + m15) * QKS + kc * 32 + q * 8];
            short8 bf = *(const short8*)&Kt[(ni * 16 + m15) * QKS + kc * 32 + q * 8];
            a1 = __builtin_amdgcn_mfma_f32_16x16x32_bf16(af, bf, a1, 0, 0, 0);
        }
        #pragma unroll
        for (int rr = 0; rr < 4; rr++) {
            const int t = mi * 16 + q * 4 + rr, s = ni * 16 + m15;
            Am[t * AMS + s] = (t >= s) ? f2bf(a1[rr]) : (short)0;
        }
    }
    __syncthreads();

    // GEMM2: O_intra = Am(32x32) @ V(32x128) -> O global (f32)
    {
        const int mi = wave >> 1, nb = (wave & 1) * 4;
        short8 af = *(const short8*)&Am[(mi * 16 + m15) * AMS + q * 8];
        #pragma unroll
        for (int jj = 0; jj < 4; jj++) {
            short8 bf = *(const short8*)&VT[((nb + jj) * 16 + m15) * VTS + q * 8];
            f32x4 a2 = (f32x4){0.f, 0.f, 0.f, 0.f};
            a2 = __builtin_amdgcn_mfma_f32_16x16x32_bf16(af, bf, a2, 0, 0, 0);
            #pragma unroll
            for (int rr = 0; rr < 4; rr++)
                O[rowbase + (size_t)(mi * 16 + q * 4 + rr) * 1024 + (nb + jj) * 16 + m15] = a2[rr];
        }
    }

    // GEMM3: S_local[kch][vch] = Kh^T @ V -> SS bf16
    {
        const size_t sbase = (size_t)(bh * NSEG + seg) * 16384;
        #pragma unroll
        for (int m2 = 0; m2 < 2; m2++) {
            const int mrow = wave * 2 + m2;
            short8 af = *(const short8*)&KhT[(mrow * 16 + m15) * VTS + q * 8];
            #pragma unroll
            for (int ni = 0; ni < 8; ni++) {
                short8 bf = *(const short8*)&VT[(ni * 16 + m15) * VTS + q * 8];
                f32x4 a3 = (f32x4){0.f, 0.f, 0.f, 0.f};
                a3 = __builtin_amdgcn_mfma_f32_16x16x32_bf16(af, bf, a3, 0, 0, 0);
                #pragma unroll
                for (int rr = 0; rr < 4; rr++)
                    SS[sbase + (size_t)(mrow * 16 + q * 4 + rr) * 128 + ni * 16 + m15] =
                        f2bf(a3[rr]);
            }
        }
    }
}

// ---------------- phase B: stitch segment states (parallel over elements) ----------------
__global__ __launch_bounds__(256) void stitch(
    short* __restrict__ SS, const float* __restrict__ DSEG)
{
    const int slice = blockIdx.x;   // 0..7 (slice of the 16384-element state)
    const int bh = blockIdx.y, tid = threadIdx.x;
    __shared__ float dloc[NSEG][16];
    dloc[tid >> 4][tid & 15] = DSEG[(bh * NSEG + (tid >> 4)) * 128 + slice * 16 + (tid & 15)];
    __syncthreads();
    float run[8];
    #pragma unroll
    for (int j = 0; j < 8; j++) run[j] = 0.f;
    for (int seg = 0; seg < NSEG; seg++) {
        const size_t base = (size_t)(bh * NSEG + seg) * 16384 + slice * 2048;
        #pragma unroll
        for (int j = 0; j < 8; j++) {
            const int e = j * 256 + tid;
            float tmp = bitf(SS[base + e]);
            SS[base + e] = f2bf(run[j]);               // S_in for this segment
            run[j] = fmaf(run[j], dloc[seg][(e >> 7)], tmp);
        }
    }
}

// ---------------- phase C: o_t += Q~_t @ S_in ----------------
__global__ __launch_bounds__(256) void correction(
    const short* __restrict__ QT, const short* __restrict__ SS, float* __restrict__ O)
{
    const int seg = blockIdx.x + 1;  // seg 0 has S_in = 0
    const int bh = blockIdx.y;
    const int b = bh >> 3, h = bh & 7;
    const int tid = threadIdx.x;
    __shared__ float qt[SEGLEN][128];
    const size_t rowbase = (size_t)(b * 512 + seg * SEGLEN) * 1024 + h * 128;
    if (tid < 128) {
        for (int t = 0; t < SEGLEN; t++)
            qt[t][tid] = bitf(QT[rowbase + (size_t)t * 1024 + tid]);
    }
    __syncthreads();
    const size_t sbase = (size_t)(bh * NSEG + seg) * 16384;
    const int v = tid & 127, th = tid >> 7;  // th: half of t-range
    float acc[SEGLEN / 2];
    #pragma unroll
    for (int tt = 0; tt < SEGLEN / 2; tt++) acc[tt] = 0.f;
    for (int k = 0; k < 128; k++) {
        float sv = bitf(SS[sbase + (size_t)k * 128 + v]);
        #pragma unroll
        for (int tt = 0; tt < SEGLEN / 2; tt++)
            acc[tt] = fmaf(qt[th * (SEGLEN / 2) + tt][k], sv, acc[tt]);
    }
    #pragma unroll
    for (int tt = 0; tt < SEGLEN / 2; tt++) {
        const int t = th * (SEGLEN / 2) + tt;
        O[rowbase + (size_t)t * 1024 + v] += acc[tt];
    }
}

// ---------------- gated RMSNorm -> bf16 (into Obf) ----------------
__global__ __launch_bounds__(128) void gnorm(
    const float* __restrict__ O, const short* __restrict__ G,
    const float* __restrict__ gnw, short* __restrict__ NR)
{
    const int row = blockIdx.x;          // (b*T + t)*H + h
    const int bt = row >> 3, h = row & 7;
    const int v = threadIdx.x;
    const size_t idx = (size_t)bt * 1024 + h * 128 + v;
    float o = O[idx];
    float ss = o * o;
    for (int off = 32; off; off >>= 1) ss += __shfl_down(ss, off);
    __shared__ float w2[2];
    if ((v & 63) == 0) w2[v >> 6] = ss;
    __syncthreads();
    float ms = (w2[0] + w2[1]) * (1.f / 128.f);
    float r = rsqrtf(ms + 1e-5f);
    float g = bitf(G[idx]);
    float sg = g / (1.f + expf(-g));     // g * sigmoid(g)
    NR[idx] = f2bf(o * r * gnw[v] * sg);
}

extern "C" void kernel_launch(void* const* d_in, const int* in_sizes, int n_in,
                              void* d_out, int out_size, void* d_ws, size_t ws_size,
                              hipStream_t stream)
{
    const float* X    = (const float*)d_in[0];
    const float* Wq   = (const float*)d_in[1];
    const float* Wk   = (const float*)d_in[2];
    const float* Wv   = (const float*)d_in[3];
    const float* Wg   = (const float*)d_in[4];
    const float* Wgk1 = (const float*)d_in[5];
    const float* Wgk2 = (const float*)d_in[6];
    const float* bgk2 = (const float*)d_in[7];
    const float* gnw  = (const float*)d_in[8];
    const float* Wo   = (const float*)d_in[9];
    float* OUT = (float*)d_out;   // reference output is float32

    // workspace layout (~32.1 MiB):
    short* QKVG = (short*)d_ws;               // 4 x 1M bf16 (Q,K,V,G)     [8 MiB]
    short* GK   = QKVG + (4u << 20);          // 1M bf16: GK, then Q~      [2 MiB]
    float* Ob   = (float*)(GK + (1u << 20));  // 1M f32                    [4 MiB]
    short* SS   = (short*)(Ob + (1u << 20));  // 16bh x 16seg x 128x128 bf16 [8 MiB]
    float* DS   = (float*)(SS + (4u << 20));  // 32K f32                   [128 KiB]
    short* WT   = (short*)(DS + 32768);       // 5 x 1M bf16 (W^T)         [10 MiB]
    short* Obf  = QKVG;                       // alias Q (dead after correction)

    cast_wt<<<dim3(32, 32, 5), 256, 0, stream>>>(Wq, Wk, Wv, Wg, Wo, WT);
    proj_gemm<<<dim3(8, 8, 4), 256, 0, stream>>>(X, WT, QKVG);
    gk_proj<<<dim3(BT), 256, 0, stream>>>(X, Wgk1, Wgk2, bgk2, GK);
    scan_chunk<<<dim3(NSEG, NBH), 256, 0, stream>>>(
        QKVG, QKVG + (1u << 20), QKVG + (2u << 20), GK, Ob, SS, DS);
    stitch<<<dim3(8, NBH), 256, 0, stream>>>(SS, DS);
    correction<<<dim3(NSEG - 1, NBH), 256, 0, stream>>>(GK, SS, Ob);
    gnorm<<<dim3(BT * NH), 128, 0, stream>>>(Ob, QKVG + (3u << 20), gnw, Obf);
    wo_gemm<<<dim3(8, 8), 256, 0, stream>>>(Obf, WT + (4u << 20), OUT);
}

// Round 8
// 181.499 us; speedup vs baseline: 2.4600x; 1.1265x over previous
//
#include <hip/hip_runtime.h>
#include <hip/hip_bf16.h>
#include <math.h>

#define BT     1024   // B*T
#define NH     8
#define SEGLEN 32
#define NSEG   16     // segments per sequence (T=512)
#define NBH    16     // B*H
#define QKS    136    // Qt/Kt LDS row stride (shorts)
#define VTS    40     // VT/KhT LDS row stride
#define AMS    40     // Am LDS row stride

typedef __attribute__((ext_vector_type(8))) short short8;
typedef __attribute__((ext_vector_type(4))) short sh4;
typedef __attribute__((ext_vector_type(4))) float f32x4;

__device__ __forceinline__ float bitf(short u) {
    union { float f; unsigned i; } x; x.i = ((unsigned)(unsigned short)u) << 16; return x.f;
}
__device__ __forceinline__ short f2bf(float f) {   // RNE f32->bf16
    union { float f; unsigned u; } x; x.f = f;
    unsigned r = x.u + 0x7FFF + ((x.u >> 16) & 1);
    return (short)(r >> 16);
}
// async global->LDS, 16B per lane; LDS dest = wave-uniform base + lane*16
__device__ __forceinline__ void gload_lds16(const short* g, short* l) {
    __builtin_amdgcn_global_load_lds(
        (const __attribute__((address_space(1))) unsigned int*)g,
        (__attribute__((address_space(3))) unsigned int*)l, 16, 0, 0);
}

// ---------------- cast X f32 -> bf16 ----------------
__global__ __launch_bounds__(256) void cast_x(
    const float* __restrict__ X, short* __restrict__ Xb)
{
    const int i = (blockIdx.x * 256 + threadIdx.x) * 8;
    float4 a = *(const float4*)(X + i);
    float4 b = *(const float4*)(X + i + 4);
    short8 v;
    v[0] = f2bf(a.x); v[1] = f2bf(a.y); v[2] = f2bf(a.z); v[3] = f2bf(a.w);
    v[4] = f2bf(b.x); v[5] = f2bf(b.y); v[6] = f2bf(b.z); v[7] = f2bf(b.w);
    *(short8*)(Xb + i) = v;
}

// ---------------- transpose+cast: W[k][n] f32 -> WT[n][k] bf16, 5 weights ----------------
__global__ __launch_bounds__(256) void cast_wt(
    const float* __restrict__ Wq, const float* __restrict__ Wk,
    const float* __restrict__ Wv, const float* __restrict__ Wg,
    const float* __restrict__ Wo, short* __restrict__ WT)
{
    const int z = blockIdx.z;
    const float* W = (z == 0) ? Wq : (z == 1) ? Wk : (z == 2) ? Wv : (z == 3) ? Wg : Wo;
    short* T = WT + (size_t)z * (1u << 20);
    __shared__ float tile[32][33];
    const int tid = threadIdx.x;
    const int k0 = blockIdx.y * 32, n0 = blockIdx.x * 32;
    const int row = tid >> 3, c4 = (tid & 7) << 2;
    float4 f = *(const float4*)(W + (size_t)(k0 + row) * 1024 + n0 + c4);
    tile[row][c4 + 0] = f.x; tile[row][c4 + 1] = f.y;
    tile[row][c4 + 2] = f.z; tile[row][c4 + 3] = f.w;
    __syncthreads();
    short* o = T + (size_t)(n0 + row) * 1024 + k0 + c4;
    o[0] = f2bf(tile[c4 + 0][row]); o[1] = f2bf(tile[c4 + 1][row]);
    o[2] = f2bf(tile[c4 + 2][row]); o[3] = f2bf(tile[c4 + 3][row]);
}

// ---------------- MFMA GEMM: Xb(bf16)@W -> bf16 out, fused over 4 weights ----------------
// tile 64(M) x 128(N), BK=64; staging via global_load_lds (16B/lane);
// LDS layout [k8][row][8] is lane-contiguous for the DMA.
__global__ __launch_bounds__(256) void proj_gemm(
    const short* __restrict__ Xb, const short* __restrict__ WT,
    short* __restrict__ QKVG)
{
    const int z = blockIdx.z;
    const float scale = (z == 0) ? 0.08838834764831845f : 1.0f;  // HK^-0.5 on q
    short* C = QKVG + (size_t)z * (1u << 20);
    const short* B = WT + (size_t)z * (1u << 20);

    __shared__ __align__(16) short As[8 * 64 * 8];    // 8 KB
    __shared__ __align__(16) short Bs[8 * 128 * 8];   // 16 KB
    const int tid = threadIdx.x;
    const int wave = tid >> 6, lane = tid & 63;
    const int wm = (wave >> 1) * 32, wn = (wave & 1) * 64;
    const int m15 = lane & 15, q = lane >> 4;
    const int m0 = blockIdx.y * 64, n0 = blockIdx.x * 128;

    f32x4 acc[2][4];
    #pragma unroll
    for (int i = 0; i < 2; i++)
        #pragma unroll
        for (int j = 0; j < 4; j++)
            acc[i][j] = (f32x4){0.f, 0.f, 0.f, 0.f};

    for (int kb0 = 0; kb0 < 1024; kb0 += 64) {
        __syncthreads();                       // previous iter's LDS reads done
        #pragma unroll
        for (int c = 0; c < 2; c++) {
            const int k8 = wave * 2 + c;
            gload_lds16(Xb + (size_t)(m0 + lane) * 1024 + kb0 + k8 * 8,
                        &As[(k8 * 64) * 8]);
            #pragma unroll
            for (int rh = 0; rh < 2; rh++)
                gload_lds16(B + (size_t)(n0 + rh * 64 + lane) * 1024 + kb0 + k8 * 8,
                            &Bs[(k8 * 128 + rh * 64) * 8]);
        }
        __syncthreads();                       // vmcnt(0) drain -> data visible
        #pragma unroll
        for (int s = 0; s < 2; s++) {
            const int k8 = s * 4 + q;
            short8 af[2], bf[4];
            #pragma unroll
            for (int i = 0; i < 2; i++)
                af[i] = *(const short8*)&As[(k8 * 64 + wm + i * 16 + m15) * 8];
            #pragma unroll
            for (int j = 0; j < 4; j++)
                bf[j] = *(const short8*)&Bs[(k8 * 128 + wn + j * 16 + m15) * 8];
            #pragma unroll
            for (int i = 0; i < 2; i++)
                #pragma unroll
                for (int j = 0; j < 4; j++)
                    acc[i][j] = __builtin_amdgcn_mfma_f32_16x16x32_bf16(af[i], bf[j], acc[i][j], 0, 0, 0);
        }
    }
    #pragma unroll
    for (int i = 0; i < 2; i++)
        #pragma unroll
        for (int j = 0; j < 4; j++)
            #pragma unroll
            for (int rr = 0; rr < 4; rr++)
                C[(size_t)(m0 + wm + i * 16 + q * 4 + rr) * 1024 + n0 + wn + j * 16 + m15] =
                    f2bf(acc[i][j][rr] * scale);
}

// ---------------- MFMA GEMM: Obf(bf16)@WoT -> out f32; tile 64x64 ----------------
__global__ __launch_bounds__(256) void wo_gemm(
    const short* __restrict__ A, const short* __restrict__ B, float* __restrict__ C)
{
    __shared__ __align__(16) short As[8 * 64 * 8];    // 8 KB
    __shared__ __align__(16) short Bs[8 * 64 * 8];    // 8 KB
    const int tid = threadIdx.x;
    const int wave = tid >> 6, lane = tid & 63;
    const int wm = (wave >> 1) * 32, wn = (wave & 1) * 32;
    const int m15 = lane & 15, q = lane >> 4;
    const int m0 = blockIdx.y * 64, n0 = blockIdx.x * 64;

    f32x4 acc[2][2];
    #pragma unroll
    for (int i = 0; i < 2; i++)
        #pragma unroll
        for (int j = 0; j < 2; j++)
            acc[i][j] = (f32x4){0.f, 0.f, 0.f, 0.f};

    for (int kb0 = 0; kb0 < 1024; kb0 += 64) {
        __syncthreads();
        #pragma unroll
        for (int c = 0; c < 2; c++) {
            const int k8 = wave * 2 + c;
            gload_lds16(A + (size_t)(m0 + lane) * 1024 + kb0 + k8 * 8, &As[(k8 * 64) * 8]);
            gload_lds16(B + (size_t)(n0 + lane) * 1024 + kb0 + k8 * 8, &Bs[(k8 * 64) * 8]);
        }
        __syncthreads();
        #pragma unroll
        for (int s = 0; s < 2; s++) {
            const int k8 = s * 4 + q;
            short8 af[2], bf[2];
            #pragma unroll
            for (int i = 0; i < 2; i++)
                af[i] = *(const short8*)&As[(k8 * 64 + wm + i * 16 + m15) * 8];
            #pragma unroll
            for (int j = 0; j < 2; j++)
                bf[j] = *(const short8*)&Bs[(k8 * 64 + wn + j * 16 + m15) * 8];
            #pragma unroll
            for (int i = 0; i < 2; i++)
                #pragma unroll
                for (int j = 0; j < 2; j++)
                    acc[i][j] = __builtin_amdgcn_mfma_f32_16x16x32_bf16(af[i], bf[j], acc[i][j], 0, 0, 0);
        }
    }
    #pragma unroll
    for (int i = 0; i < 2; i++)
        #pragma unroll
        for (int j = 0; j < 2; j++)
            #pragma unroll
            for (int rr = 0; rr < 4; rr++)
                C[(size_t)(m0 + wm + i * 16 + q * 4 + rr) * 1024 + n0 + wn + j * 16 + m15] =
                    acc[i][j][rr];
}

// ---------------- low-rank gate: gk = logsigmoid(x@Wgk1@Wgk2 + b)/16 -> bf16 ----------------
__global__ __launch_bounds__(256) void gk_proj(
    const float* __restrict__ X, const float* __restrict__ Wgk1,
    const float* __restrict__ Wgk2, const float* __restrict__ bgk2,
    short* __restrict__ GK)
{
    const int row = blockIdx.x, tid = threadIdx.x;
    float p[16];
    #pragma unroll
    for (int j = 0; j < 16; j++) p[j] = 0.f;
    for (int d = tid; d < 1024; d += 256) {
        float xv = X[(size_t)row * 1024 + d];
        #pragma unroll
        for (int j = 0; j < 16; j++)
            p[j] = fmaf(xv, Wgk1[d * 16 + j], p[j]);
    }
    #pragma unroll
    for (int j = 0; j < 16; j++)
        for (int off = 32; off; off >>= 1) p[j] += __shfl_down(p[j], off);
    __shared__ float zp[4][16];
    __shared__ float z[16];
    const int lane = tid & 63, w = tid >> 6;
    if (lane == 0) {
        #pragma unroll
        for (int j = 0; j < 16; j++) zp[w][j] = p[j];
    }
    __syncthreads();
    if (tid < 16) z[tid] = zp[0][tid] + zp[1][tid] + zp[2][tid] + zp[3][tid];
    __syncthreads();
    for (int c = tid; c < 1024; c += 256) {
        float acc = bgk2[c];
        #pragma unroll
        for (int j = 0; j < 16; j++)
            acc = fmaf(z[j], Wgk2[j * 1024 + c], acc);
        float ls = fminf(acc, 0.f) - log1pf(expf(-fabsf(acc)));  // logsigmoid
        GK[(size_t)row * 1024 + c] = f2bf(ls * (1.f / 16.f));
    }
}

// ---------------- phase A: chunked scan via MFMA ----------------
__global__ __launch_bounds__(256) void scan_chunk(
    const short* __restrict__ Q, const short* __restrict__ K,
    const short* __restrict__ V, short* GKQT,
    float* __restrict__ O, short* __restrict__ SS, float* __restrict__ DSEG)
{
    const int seg = blockIdx.x;   // 0..15
    const int bh  = blockIdx.y;   // 0..15
    const int b = bh >> 3, h = bh & 7;
    const int tid = threadIdx.x;
    const size_t rowbase = (size_t)(b * 512 + seg * SEGLEN) * 1024 + h * 128;

    __shared__ __align__(16) short Qt[32 * QKS];
    __shared__ __align__(16) short Kt[32 * QKS];
    __shared__ __align__(16) short Vs[32 * 128];
    __shared__ __align__(16) short VT[128 * VTS];
    __shared__ __align__(16) short KhT[128 * VTS];
    __shared__ __align__(16) short Am[32 * AMS];

    if (tid < 128) {
        const int ch = tid;
        float gsum = 0.f;
        float ktf[32];
        #pragma unroll
        for (int t = 0; t < 32; t++) {
            const size_t a = rowbase + (size_t)t * 1024 + ch;
            float g  = bitf(GKQT[a]);
            float kv = bitf(K[a]);
            float qv = bitf(Q[a]);
            gsum += g;
            float eg  = expf(gsum);
            float emg = expf(-gsum);
            short qts = f2bf(qv * eg);
            Qt[t * QKS + ch] = qts;
            GKQT[a] = qts;                       // write Q~ over GK
            float ktv = kv * emg;
            Kt[t * QKS + ch] = f2bf(ktv);
            ktf[t] = ktv;
        }
        float eGend = expf(gsum);
        DSEG[(bh * NSEG + seg) * 128 + ch] = eGend;
        #pragma unroll
        for (int t4 = 0; t4 < 8; t4++) {
            sh4 p;
            p[0] = f2bf(ktf[4 * t4 + 0] * eGend);
            p[1] = f2bf(ktf[4 * t4 + 1] * eGend);
            p[2] = f2bf(ktf[4 * t4 + 2] * eGend);
            p[3] = f2bf(ktf[4 * t4 + 3] * eGend);
            *(sh4*)&KhT[ch * VTS + 4 * t4] = p;
        }
    } else {
        const int u = tid - 128;
        #pragma unroll
        for (int i = 0; i < 4; i++) {
            const int idx = u + i * 128;          // short8 index, 512 total
            const int t = idx >> 4, c = idx & 15;
            short8 vv = *(const short8*)&V[rowbase + (size_t)t * 1024 + c * 8];
            *(short8*)&Vs[t * 128 + c * 8] = vv;
        }
    }
    __syncthreads();
    {
        const int ch = tid >> 1, t0 = (tid & 1) * 16;
        #pragma unroll
        for (int j = 0; j < 4; j++) {
            sh4 p;
            p[0] = Vs[(t0 + 4 * j + 0) * 128 + ch];
            p[1] = Vs[(t0 + 4 * j + 1) * 128 + ch];
            p[2] = Vs[(t0 + 4 * j + 2) * 128 + ch];
            p[3] = Vs[(t0 + 4 * j + 3) * 128 + ch];
            *(sh4*)&VT[ch * VTS + t0 + 4 * j] = p;
        }
    }
    __syncthreads();

    const int wave = tid >> 6, lane = tid & 63;
    const int m15 = lane & 15, q = lane >> 4;

    // GEMM1: A = Qt(32x128) @ Kt^T, causal mask, -> Am bf16
    {
        const int mi = wave >> 1, ni = wave & 1;
        f32x4 a1 = (f32x4){0.f, 0.f, 0.f, 0.f};
        #pragma unroll
        for (int kc = 0; kc < 4; kc++) {
            short8 af = *(const short8*)&Qt[(mi * 16 + m15) * QKS + kc * 32 + q * 8];
            short8 bf = *(const short8*)&Kt[(ni * 16 + m15) * QKS + kc * 32 + q * 8];
            a1 = __builtin_amdgcn_mfma_f32_16x16x32_bf16(af, bf, a1, 0, 0, 0);
        }
        #pragma unroll
        for (int rr = 0; rr < 4; rr++) {
            const int t = mi * 16 + q * 4 + rr, s = ni * 16 + m15;
            Am[t * AMS + s] = (t >= s) ? f2bf(a1[rr]) : (short)0;
        }
    }
    __syncthreads();

    // GEMM2: O_intra = Am(32x32) @ V(32x128) -> O global (f32)
    {
        const int mi = wave >> 1, nb = (wave & 1) * 4;
        short8 af = *(const short8*)&Am[(mi * 16 + m15) * AMS + q * 8];
        #pragma unroll
        for (int jj = 0; jj < 4; jj++) {
            short8 bf = *(const short8*)&VT[((nb + jj) * 16 + m15) * VTS + q * 8];
            f32x4 a2 = (f32x4){0.f, 0.f, 0.f, 0.f};
            a2 = __builtin_amdgcn_mfma_f32_16x16x32_bf16(af, bf, a2, 0, 0, 0);
            #pragma unroll
            for (int rr = 0; rr < 4; rr++)
                O[rowbase + (size_t)(mi * 16 + q * 4 + rr) * 1024 + (nb + jj) * 16 + m15] = a2[rr];
        }
    }

    // GEMM3: S_local[kch][vch] = Kh^T @ V -> SS bf16
    {
        const size_t sbase = (size_t)(bh * NSEG + seg) * 16384;
        #pragma unroll
        for (int m2 = 0; m2 < 2; m2++) {
            const int mrow = wave * 2 + m2;
            short8 af = *(const short8*)&KhT[(mrow * 16 + m15) * VTS + q * 8];
            #pragma unroll
            for (int ni = 0; ni < 8; ni++) {
                short8 bf = *(const short8*)&VT[(ni * 16 + m15) * VTS + q * 8];
                f32x4 a3 = (f32x4){0.f, 0.f, 0.f, 0.f};
                a3 = __builtin_amdgcn_mfma_f32_16x16x32_bf16(af, bf, a3, 0, 0, 0);
                #pragma unroll
                for (int rr = 0; rr < 4; rr++)
                    SS[sbase + (size_t)(mrow * 16 + q * 4 + rr) * 128 + ni * 16 + m15] =
                        f2bf(a3[rr]);
            }
        }
    }
}

// ---------------- phase B: stitch segment states (parallel over elements) ----------------
__global__ __launch_bounds__(256) void stitch(
    short* __restrict__ SS, const float* __restrict__ DSEG)
{
    const int slice = blockIdx.x;   // 0..7
    const int bh = blockIdx.y, tid = threadIdx.x;
    __shared__ float dloc[NSEG][16];
    dloc[tid >> 4][tid & 15] = DSEG[(bh * NSEG + (tid >> 4)) * 128 + slice * 16 + (tid & 15)];
    __syncthreads();
    float run[8];
    #pragma unroll
    for (int j = 0; j < 8; j++) run[j] = 0.f;
    for (int seg = 0; seg < NSEG; seg++) {
        const size_t base = (size_t)(bh * NSEG + seg) * 16384 + slice * 2048;
        #pragma unroll
        for (int j = 0; j < 8; j++) {
            const int e = j * 256 + tid;
            float tmp = bitf(SS[base + e]);
            SS[base + e] = f2bf(run[j]);               // S_in for this segment
            run[j] = fmaf(run[j], dloc[seg][(e >> 7)], tmp);
        }
    }
}

// ---------------- phase C: o_t += Q~_t @ S_in ----------------
__global__ __launch_bounds__(256) void correction(
    const short* __restrict__ QT, const short* __restrict__ SS, float* __restrict__ O)
{
    const int seg = blockIdx.x + 1;  // seg 0 has S_in = 0
    const int bh = blockIdx.y;
    const int b = bh >> 3, h = bh & 7;
    const int tid = threadIdx.x;
    __shared__ float qt[SEGLEN][128];
    const size_t rowbase = (size_t)(b * 512 + seg * SEGLEN) * 1024 + h * 128;
    if (tid < 128) {
        for (int t = 0; t < SEGLEN; t++)
            qt[t][tid] = bitf(QT[rowbase + (size_t)t * 1024 + tid]);
    }
    __syncthreads();
    const size_t sbase = (size_t)(bh * NSEG + seg) * 16384;
    const int v = tid & 127, th = tid >> 7;
    float acc[SEGLEN / 2];
    #pragma unroll
    for (int tt = 0; tt < SEGLEN / 2; tt++) acc[tt] = 0.f;
    for (int k = 0; k < 128; k++) {
        float sv = bitf(SS[sbase + (size_t)k * 128 + v]);
        #pragma unroll
        for (int tt = 0; tt < SEGLEN / 2; tt++)
            acc[tt] = fmaf(qt[th * (SEGLEN / 2) + tt][k], sv, acc[tt]);
    }
    #pragma unroll
    for (int tt = 0; tt < SEGLEN / 2; tt++) {
        const int t = th * (SEGLEN / 2) + tt;
        O[rowbase + (size_t)t * 1024 + v] += acc[tt];
    }
}

// ---------------- gated RMSNorm -> bf16 (into Obf) ----------------
__global__ __launch_bounds__(128) void gnorm(
    const float* __restrict__ O, const short* __restrict__ G,
    const float* __restrict__ gnw, short* __restrict__ NR)
{
    const int row = blockIdx.x;
    const int bt = row >> 3, h = row & 7;
    const int v = threadIdx.x;
    const size_t idx = (size_t)bt * 1024 + h * 128 + v;
    float o = O[idx];
    float ss = o * o;
    for (int off = 32; off; off >>= 1) ss += __shfl_down(ss, off);
    __shared__ float w2[2];
    if ((v & 63) == 0) w2[v >> 6] = ss;
    __syncthreads();
    float ms = (w2[0] + w2[1]) * (1.f / 128.f);
    float r = rsqrtf(ms + 1e-5f);
    float g = bitf(G[idx]);
    float sg = g / (1.f + expf(-g));
    NR[idx] = f2bf(o * r * gnw[v] * sg);
}

extern "C" void kernel_launch(void* const* d_in, const int* in_sizes, int n_in,
                              void* d_out, int out_size, void* d_ws, size_t ws_size,
                              hipStream_t stream)
{
    const float* X    = (const float*)d_in[0];
    const float* Wq   = (const float*)d_in[1];
    const float* Wk   = (const float*)d_in[2];
    const float* Wv   = (const float*)d_in[3];
    const float* Wg   = (const float*)d_in[4];
    const float* Wgk1 = (const float*)d_in[5];
    const float* Wgk2 = (const float*)d_in[6];
    const float* bgk2 = (const float*)d_in[7];
    const float* gnw  = (const float*)d_in[8];
    const float* Wo   = (const float*)d_in[9];
    float* OUT = (float*)d_out;   // reference output is float32

    // workspace layout (~32.1 MiB):
    short* QKVG = (short*)d_ws;               // 4 x 1M bf16 (Q,K,V,G)     [8 MiB]
    short* GK   = QKVG + (4u << 20);          // 1M bf16: Xb -> GK -> Q~   [2 MiB]
    float* Ob   = (float*)(GK + (1u << 20));  // 1M f32                    [4 MiB]
    short* SS   = (short*)(Ob + (1u << 20));  // 16bh x 16seg x 128x128 bf16 [8 MiB]
    float* DS   = (float*)(SS + (4u << 20));  // 32K f32                   [128 KiB]
    short* WT   = (short*)(DS + 32768);       // 5 x 1M bf16 (W^T)         [10 MiB]
    short* Obf  = QKVG;                       // alias Q (dead after correction)
    short* Xb   = GK;                         // alias GK (dead until gk_proj)

    cast_wt<<<dim3(32, 32, 5), 256, 0, stream>>>(Wq, Wk, Wv, Wg, Wo, WT);
    cast_x<<<dim3(512), 256, 0, stream>>>(X, Xb);
    proj_gemm<<<dim3(8, 16, 4), 256, 0, stream>>>(Xb, WT, QKVG);
    gk_proj<<<dim3(BT), 256, 0, stream>>>(X, Wgk1, Wgk2, bgk2, GK);   // overwrites Xb
    scan_chunk<<<dim3(NSEG, NBH), 256, 0, stream>>>(
        QKVG, QKVG + (1u << 20), QKVG + (2u << 20), GK, Ob, SS, DS);
    stitch<<<dim3(8, NBH), 256, 0, stream>>>(SS, DS);
    correction<<<dim3(NSEG - 1, NBH), 256, 0, stream>>>(GK, SS, Ob);
    gnorm<<<dim3(BT * NH), 128, 0, stream>>>(Ob, QKVG + (3u << 20), gnw, Obf);
    wo_gemm<<<dim3(16, 16), 256, 0, stream>>>(Obf, WT + (4u << 20), OUT);
}

// Round 9
// 174.123 us; speedup vs baseline: 2.5643x; 1.0424x over previous
//
#include <hip/hip_runtime.h>
#include <hip/hip_bf16.h>
#include <math.h>

#define BT     1024   // B*T
#define NH     8
#define SEGLEN 32
#define NSEG   16     // segments per sequence (T=512)
#define NBH    16     // B*H
#define QKS    136    // Qt/Kt LDS row stride (shorts)
#define VTS    40     // VT/KhT LDS row stride
#define AMS    40     // Am LDS row stride

typedef __attribute__((ext_vector_type(8))) short short8;
typedef __attribute__((ext_vector_type(4))) short sh4;
typedef __attribute__((ext_vector_type(4))) float f32x4;

__device__ __forceinline__ float bitf(short u) {
    union { float f; unsigned i; } x; x.i = ((unsigned)(unsigned short)u) << 16; return x.f;
}
__device__ __forceinline__ short f2bf(float f) {   // RNE f32->bf16
    union { float f; unsigned u; } x; x.f = f;
    unsigned r = x.u + 0x7FFF + ((x.u >> 16) & 1);
    return (short)(r >> 16);
}
// async global->LDS, 16B per lane; LDS dest = wave-uniform base + lane*16
__device__ __forceinline__ void gload_lds16(const short* g, short* l) {
    __builtin_amdgcn_global_load_lds(
        (const __attribute__((address_space(1))) unsigned int*)g,
        (__attribute__((address_space(3))) unsigned int*)l, 16, 0, 0);
}

// ---------------- fused pre-cast: W^T (z=0..4) and X (z=5) -> bf16 ----------------
__global__ __launch_bounds__(256) void cast_all(
    const float* __restrict__ Wq, const float* __restrict__ Wk,
    const float* __restrict__ Wv, const float* __restrict__ Wg,
    const float* __restrict__ Wo, const float* __restrict__ X,
    short* __restrict__ WT, short* __restrict__ Xb)
{
    const int z = blockIdx.z;
    const int tid = threadIdx.x;
    if (z == 5) {                           // cast X: 1024 blocks x 1024 floats
        const int id = blockIdx.y * 32 + blockIdx.x;
        const int i = id * 1024 + tid * 4;
        float4 a = *(const float4*)(X + i);
        sh4 v;
        v[0] = f2bf(a.x); v[1] = f2bf(a.y); v[2] = f2bf(a.z); v[3] = f2bf(a.w);
        *(sh4*)(Xb + i) = v;
        return;
    }
    const float* W = (z == 0) ? Wq : (z == 1) ? Wk : (z == 2) ? Wv : (z == 3) ? Wg : Wo;
    short* T = WT + (size_t)z * (1u << 20);
    __shared__ float tile[32][33];
    const int k0 = blockIdx.y * 32, n0 = blockIdx.x * 32;
    const int row = tid >> 3, c4 = (tid & 7) << 2;
    float4 f = *(const float4*)(W + (size_t)(k0 + row) * 1024 + n0 + c4);
    tile[row][c4 + 0] = f.x; tile[row][c4 + 1] = f.y;
    tile[row][c4 + 2] = f.z; tile[row][c4 + 3] = f.w;
    __syncthreads();
    short* o = T + (size_t)(n0 + row) * 1024 + k0 + c4;
    o[0] = f2bf(tile[c4 + 0][row]); o[1] = f2bf(tile[c4 + 1][row]);
    o[2] = f2bf(tile[c4 + 2][row]); o[3] = f2bf(tile[c4 + 3][row]);
}

// ---------------- MFMA GEMM: Xb(bf16)@W -> bf16 out, fused over 4 weights ----------------
__global__ __launch_bounds__(256) void proj_gemm(
    const short* __restrict__ Xb, const short* __restrict__ WT,
    short* __restrict__ QKVG)
{
    const int z = blockIdx.z;
    const float scale = (z == 0) ? 0.08838834764831845f : 1.0f;  // HK^-0.5 on q
    short* C = QKVG + (size_t)z * (1u << 20);
    const short* B = WT + (size_t)z * (1u << 20);

    __shared__ __align__(16) short As[8 * 64 * 8];    // 8 KB
    __shared__ __align__(16) short Bs[8 * 128 * 8];   // 16 KB
    const int tid = threadIdx.x;
    const int wave = tid >> 6, lane = tid & 63;
    const int wm = (wave >> 1) * 32, wn = (wave & 1) * 64;
    const int m15 = lane & 15, q = lane >> 4;
    const int m0 = blockIdx.y * 64, n0 = blockIdx.x * 128;

    f32x4 acc[2][4];
    #pragma unroll
    for (int i = 0; i < 2; i++)
        #pragma unroll
        for (int j = 0; j < 4; j++)
            acc[i][j] = (f32x4){0.f, 0.f, 0.f, 0.f};

    for (int kb0 = 0; kb0 < 1024; kb0 += 64) {
        __syncthreads();
        #pragma unroll
        for (int c = 0; c < 2; c++) {
            const int k8 = wave * 2 + c;
            gload_lds16(Xb + (size_t)(m0 + lane) * 1024 + kb0 + k8 * 8,
                        &As[(k8 * 64) * 8]);
            #pragma unroll
            for (int rh = 0; rh < 2; rh++)
                gload_lds16(B + (size_t)(n0 + rh * 64 + lane) * 1024 + kb0 + k8 * 8,
                            &Bs[(k8 * 128 + rh * 64) * 8]);
        }
        __syncthreads();
        #pragma unroll
        for (int s = 0; s < 2; s++) {
            const int k8 = s * 4 + q;
            short8 af[2], bf[4];
            #pragma unroll
            for (int i = 0; i < 2; i++)
                af[i] = *(const short8*)&As[(k8 * 64 + wm + i * 16 + m15) * 8];
            #pragma unroll
            for (int j = 0; j < 4; j++)
                bf[j] = *(const short8*)&Bs[(k8 * 128 + wn + j * 16 + m15) * 8];
            #pragma unroll
            for (int i = 0; i < 2; i++)
                #pragma unroll
                for (int j = 0; j < 4; j++)
                    acc[i][j] = __builtin_amdgcn_mfma_f32_16x16x32_bf16(af[i], bf[j], acc[i][j], 0, 0, 0);
        }
    }
    #pragma unroll
    for (int i = 0; i < 2; i++)
        #pragma unroll
        for (int j = 0; j < 4; j++)
            #pragma unroll
            for (int rr = 0; rr < 4; rr++)
                C[(size_t)(m0 + wm + i * 16 + q * 4 + rr) * 1024 + n0 + wn + j * 16 + m15] =
                    f2bf(acc[i][j][rr] * scale);
}

// ---------------- MFMA GEMM: Obf(bf16)@WoT -> out f32; tile 64x64 ----------------
__global__ __launch_bounds__(256) void wo_gemm(
    const short* __restrict__ A, const short* __restrict__ B, float* __restrict__ C)
{
    __shared__ __align__(16) short As[8 * 64 * 8];
    __shared__ __align__(16) short Bs[8 * 64 * 8];
    const int tid = threadIdx.x;
    const int wave = tid >> 6, lane = tid & 63;
    const int wm = (wave >> 1) * 32, wn = (wave & 1) * 32;
    const int m15 = lane & 15, q = lane >> 4;
    const int m0 = blockIdx.y * 64, n0 = blockIdx.x * 64;

    f32x4 acc[2][2];
    #pragma unroll
    for (int i = 0; i < 2; i++)
        #pragma unroll
        for (int j = 0; j < 2; j++)
            acc[i][j] = (f32x4){0.f, 0.f, 0.f, 0.f};

    for (int kb0 = 0; kb0 < 1024; kb0 += 64) {
        __syncthreads();
        #pragma unroll
        for (int c = 0; c < 2; c++) {
            const int k8 = wave * 2 + c;
            gload_lds16(A + (size_t)(m0 + lane) * 1024 + kb0 + k8 * 8, &As[(k8 * 64) * 8]);
            gload_lds16(B + (size_t)(n0 + lane) * 1024 + kb0 + k8 * 8, &Bs[(k8 * 64) * 8]);
        }
        __syncthreads();
        #pragma unroll
        for (int s = 0; s < 2; s++) {
            const int k8 = s * 4 + q;
            short8 af[2], bf[2];
            #pragma unroll
            for (int i = 0; i < 2; i++)
                af[i] = *(const short8*)&As[(k8 * 64 + wm + i * 16 + m15) * 8];
            #pragma unroll
            for (int j = 0; j < 2; j++)
                bf[j] = *(const short8*)&Bs[(k8 * 64 + wn + j * 16 + m15) * 8];
            #pragma unroll
            for (int i = 0; i < 2; i++)
                #pragma unroll
                for (int j = 0; j < 2; j++)
                    acc[i][j] = __builtin_amdgcn_mfma_f32_16x16x32_bf16(af[i], bf[j], acc[i][j], 0, 0, 0);
        }
    }
    #pragma unroll
    for (int i = 0; i < 2; i++)
        #pragma unroll
        for (int j = 0; j < 2; j++)
            #pragma unroll
            for (int rr = 0; rr < 4; rr++)
                C[(size_t)(m0 + wm + i * 16 + q * 4 + rr) * 1024 + n0 + wn + j * 16 + m15] =
                    acc[i][j][rr];
}

// ---------------- low-rank gate (bf16 X): gk = logsigmoid(x@Wgk1@Wgk2 + b)/16 ----------------
__global__ __launch_bounds__(256) void gk_proj(
    const short* __restrict__ Xb, const float* __restrict__ Wgk1,
    const float* __restrict__ Wgk2, const float* __restrict__ bgk2,
    short* __restrict__ GK)
{
    const int row = blockIdx.x, tid = threadIdx.x;
    float p[16];
    #pragma unroll
    for (int j = 0; j < 16; j++) p[j] = 0.f;
    for (int d = tid; d < 1024; d += 256) {
        float xv = bitf(Xb[(size_t)row * 1024 + d]);
        #pragma unroll
        for (int j = 0; j < 16; j++)
            p[j] = fmaf(xv, Wgk1[d * 16 + j], p[j]);
    }
    #pragma unroll
    for (int j = 0; j < 16; j++)
        for (int off = 32; off; off >>= 1) p[j] += __shfl_down(p[j], off);
    __shared__ float zp[4][16];
    __shared__ float z[16];
    const int lane = tid & 63, w = tid >> 6;
    if (lane == 0) {
        #pragma unroll
        for (int j = 0; j < 16; j++) zp[w][j] = p[j];
    }
    __syncthreads();
    if (tid < 16) z[tid] = zp[0][tid] + zp[1][tid] + zp[2][tid] + zp[3][tid];
    __syncthreads();
    for (int c = tid; c < 1024; c += 256) {
        float acc = bgk2[c];
        #pragma unroll
        for (int j = 0; j < 16; j++)
            acc = fmaf(z[j], Wgk2[j * 1024 + c], acc);
        float ls = fminf(acc, 0.f) - log1pf(expf(-fabsf(acc)));  // logsigmoid
        GK[(size_t)row * 1024 + c] = f2bf(ls * (1.f / 16.f));
    }
}

// ---------------- phase A: chunked scan via MFMA ----------------
__global__ __launch_bounds__(256) void scan_chunk(
    const short* __restrict__ Q, const short* __restrict__ K,
    const short* __restrict__ V, short* GKQT,
    float* __restrict__ O, short* __restrict__ SS, float* __restrict__ DSEG)
{
    const int seg = blockIdx.x;   // 0..15
    const int bh  = blockIdx.y;   // 0..15
    const int b = bh >> 3, h = bh & 7;
    const int tid = threadIdx.x;
    const size_t rowbase = (size_t)(b * 512 + seg * SEGLEN) * 1024 + h * 128;

    __shared__ __align__(16) short Qt[32 * QKS];
    __shared__ __align__(16) short Kt[32 * QKS];
    __shared__ __align__(16) short Vs[32 * 128];
    __shared__ __align__(16) short VT[128 * VTS];
    __shared__ __align__(16) short KhT[128 * VTS];
    __shared__ __align__(16) short Am[32 * AMS];

    if (tid < 128) {
        const int ch = tid;
        float gsum = 0.f;
        float ktf[32];
        #pragma unroll
        for (int t = 0; t < 32; t++) {
            const size_t a = rowbase + (size_t)t * 1024 + ch;
            float g  = bitf(GKQT[a]);
            float kv = bitf(K[a]);
            float qv = bitf(Q[a]);
            gsum += g;
            float eg  = expf(gsum);
            float emg = expf(-gsum);
            short qts = f2bf(qv * eg);
            Qt[t * QKS + ch] = qts;
            GKQT[a] = qts;                       // write Q~ over GK
            float ktv = kv * emg;
            Kt[t * QKS + ch] = f2bf(ktv);
            ktf[t] = ktv;
        }
        float eGend = expf(gsum);
        DSEG[(bh * NSEG + seg) * 128 + ch] = eGend;
        #pragma unroll
        for (int t4 = 0; t4 < 8; t4++) {
            sh4 p;
            p[0] = f2bf(ktf[4 * t4 + 0] * eGend);
            p[1] = f2bf(ktf[4 * t4 + 1] * eGend);
            p[2] = f2bf(ktf[4 * t4 + 2] * eGend);
            p[3] = f2bf(ktf[4 * t4 + 3] * eGend);
            *(sh4*)&KhT[ch * VTS + 4 * t4] = p;
        }
    } else {
        const int u = tid - 128;
        #pragma unroll
        for (int i = 0; i < 4; i++) {
            const int idx = u + i * 128;          // short8 index, 512 total
            const int t = idx >> 4, c = idx & 15;
            short8 vv = *(const short8*)&V[rowbase + (size_t)t * 1024 + c * 8];
            *(short8*)&Vs[t * 128 + c * 8] = vv;
        }
    }
    __syncthreads();
    {
        const int ch = tid >> 1, t0 = (tid & 1) * 16;
        #pragma unroll
        for (int j = 0; j < 4; j++) {
            sh4 p;
            p[0] = Vs[(t0 + 4 * j + 0) * 128 + ch];
            p[1] = Vs[(t0 + 4 * j + 1) * 128 + ch];
            p[2] = Vs[(t0 + 4 * j + 2) * 128 + ch];
            p[3] = Vs[(t0 + 4 * j + 3) * 128 + ch];
            *(sh4*)&VT[ch * VTS + t0 + 4 * j] = p;
        }
    }
    __syncthreads();

    const int wave = tid >> 6, lane = tid & 63;
    const int m15 = lane & 15, q = lane >> 4;

    // GEMM1: A = Qt(32x128) @ Kt^T, causal mask, -> Am bf16
    {
        const int mi = wave >> 1, ni = wave & 1;
        f32x4 a1 = (f32x4){0.f, 0.f, 0.f, 0.f};
        #pragma unroll
        for (int kc = 0; kc < 4; kc++) {
            short8 af = *(const short8*)&Qt[(mi * 16 + m15) * QKS + kc * 32 + q * 8];
            short8 bf = *(const short8*)&Kt[(ni * 16 + m15) * QKS + kc * 32 + q * 8];
            a1 = __builtin_amdgcn_mfma_f32_16x16x32_bf16(af, bf, a1, 0, 0, 0);
        }
        #pragma unroll
        for (int rr = 0; rr < 4; rr++) {
            const int t = mi * 16 + q * 4 + rr, s = ni * 16 + m15;
            Am[t * AMS + s] = (t >= s) ? f2bf(a1[rr]) : (short)0;
        }
    }
    __syncthreads();

    // GEMM2: O_intra = Am(32x32) @ V(32x128) -> O global (f32)
    {
        const int mi = wave >> 1, nb = (wave & 1) * 4;
        short8 af = *(const short8*)&Am[(mi * 16 + m15) * AMS + q * 8];
        #pragma unroll
        for (int jj = 0; jj < 4; jj++) {
            short8 bf = *(const short8*)&VT[((nb + jj) * 16 + m15) * VTS + q * 8];
            f32x4 a2 = (f32x4){0.f, 0.f, 0.f, 0.f};
            a2 = __builtin_amdgcn_mfma_f32_16x16x32_bf16(af, bf, a2, 0, 0, 0);
            #pragma unroll
            for (int rr = 0; rr < 4; rr++)
                O[rowbase + (size_t)(mi * 16 + q * 4 + rr) * 1024 + (nb + jj) * 16 + m15] = a2[rr];
        }
    }

    // GEMM3: S_local[kch][vch] = Kh^T @ V -> SS bf16
    {
        const size_t sbase = (size_t)(bh * NSEG + seg) * 16384;
        #pragma unroll
        for (int m2 = 0; m2 < 2; m2++) {
            const int mrow = wave * 2 + m2;
            short8 af = *(const short8*)&KhT[(mrow * 16 + m15) * VTS + q * 8];
            #pragma unroll
            for (int ni = 0; ni < 8; ni++) {
                short8 bf = *(const short8*)&VT[(ni * 16 + m15) * VTS + q * 8];
                f32x4 a3 = (f32x4){0.f, 0.f, 0.f, 0.f};
                a3 = __builtin_amdgcn_mfma_f32_16x16x32_bf16(af, bf, a3, 0, 0, 0);
                #pragma unroll
                for (int rr = 0; rr < 4; rr++)
                    SS[sbase + (size_t)(mrow * 16 + q * 4 + rr) * 128 + ni * 16 + m15] =
                        f2bf(a3[rr]);
            }
        }
    }
}

// ---------------- phase B: stitch segment states (parallel over elements) ----------------
__global__ __launch_bounds__(256) void stitch(
    short* __restrict__ SS, const float* __restrict__ DSEG)
{
    const int slice = blockIdx.x;   // 0..7
    const int bh = blockIdx.y, tid = threadIdx.x;
    __shared__ float dloc[NSEG][16];
    dloc[tid >> 4][tid & 15] = DSEG[(bh * NSEG + (tid >> 4)) * 128 + slice * 16 + (tid & 15)];
    __syncthreads();
    float run[8];
    #pragma unroll
    for (int j = 0; j < 8; j++) run[j] = 0.f;
    for (int seg = 0; seg < NSEG; seg++) {
        const size_t base = (size_t)(bh * NSEG + seg) * 16384 + slice * 2048;
        #pragma unroll
        for (int j = 0; j < 8; j++) {
            const int e = j * 256 + tid;
            float tmp = bitf(SS[base + e]);
            SS[base + e] = f2bf(run[j]);               // S_in for this segment
            run[j] = fmaf(run[j], dloc[seg][(e >> 7)], tmp);
        }
    }
}

// ---------------- phase C fused: o = O_intra + Q~@S_in, then gated RMSNorm -> bf16 ----------------
__global__ __launch_bounds__(256) void corr_gnorm(
    const short* __restrict__ QT, const short* __restrict__ SS,
    const float* __restrict__ O, const short* __restrict__ G,
    const float* __restrict__ gnw, short* __restrict__ Obf)
{
    const int seg = blockIdx.x;      // 0..15 (seg 0's S_in is all-zero in SS)
    const int bh = blockIdx.y;
    const int b = bh >> 3, h = bh & 7;
    const int tid = threadIdx.x;
    __shared__ float qt[SEGLEN][128];
    __shared__ float red[4][16];
    const size_t rowbase = (size_t)(b * 512 + seg * SEGLEN) * 1024 + h * 128;
    {   // load Q~ tile: thread -> row tid>>3, 16 cols
        const int t = tid >> 3, c0 = (tid & 7) * 16;
        #pragma unroll
        for (int c = 0; c < 16; c++)
            qt[t][c0 + c] = bitf(QT[rowbase + (size_t)t * 1024 + c0 + c]);
    }
    __syncthreads();
    const size_t sbase = (size_t)(bh * NSEG + seg) * 16384;
    const int v = tid & 127, th = tid >> 7;   // th: half of t-range (16 t's each)
    float acc[16];
    #pragma unroll
    for (int tt = 0; tt < 16; tt++) acc[tt] = 0.f;
    for (int k = 0; k < 128; k++) {
        float sv = bitf(SS[sbase + (size_t)k * 128 + v]);
        #pragma unroll
        for (int tt = 0; tt < 16; tt++)
            acc[tt] = fmaf(qt[th * 16 + tt][k], sv, acc[tt]);
    }
    // o = O_intra + correction; rowwise RMS over v (128 lanes = 2 waves per th group)
    float o[16], ss[16];
    #pragma unroll
    for (int tt = 0; tt < 16; tt++) {
        const int t = th * 16 + tt;
        o[tt] = O[rowbase + (size_t)t * 1024 + v] + acc[tt];
        ss[tt] = o[tt] * o[tt];
    }
    #pragma unroll
    for (int tt = 0; tt < 16; tt++)
        #pragma unroll
        for (int off = 32; off; off >>= 1)
            ss[tt] += __shfl_xor(ss[tt], off);
    const int wv = tid >> 6;
    if ((tid & 63) == 0) {
        #pragma unroll
        for (int tt = 0; tt < 16; tt++) red[wv][tt] = ss[tt];
    }
    __syncthreads();
    const float gw = gnw[v];
    #pragma unroll
    for (int tt = 0; tt < 16; tt++) {
        const int t = th * 16 + tt;
        float ms = (red[th * 2][tt] + red[th * 2 + 1][tt]) * (1.f / 128.f);
        float r = rsqrtf(ms + 1e-5f);
        float g = bitf(G[rowbase + (size_t)t * 1024 + v]);
        float sg = g / (1.f + expf(-g));
        Obf[rowbase + (size_t)t * 1024 + v] = f2bf(o[tt] * r * gw * sg);
    }
}

extern "C" void kernel_launch(void* const* d_in, const int* in_sizes, int n_in,
                              void* d_out, int out_size, void* d_ws, size_t ws_size,
                              hipStream_t stream)
{
    const float* X    = (const float*)d_in[0];
    const float* Wq   = (const float*)d_in[1];
    const float* Wk   = (const float*)d_in[2];
    const float* Wv   = (const float*)d_in[3];
    const float* Wg   = (const float*)d_in[4];
    const float* Wgk1 = (const float*)d_in[5];
    const float* Wgk2 = (const float*)d_in[6];
    const float* bgk2 = (const float*)d_in[7];
    const float* gnw  = (const float*)d_in[8];
    const float* Wo   = (const float*)d_in[9];
    float* OUT = (float*)d_out;   // reference output is float32

    // workspace layout (~34.1 MiB):
    short* QKVG = (short*)d_ws;               // 4 x 1M bf16 (Q,K,V,G)     [8 MiB]
    short* GK   = QKVG + (4u << 20);          // 1M bf16: GK -> Q~         [2 MiB]
    float* Ob   = (float*)(GK + (1u << 20));  // 1M f32                    [4 MiB]
    short* SS   = (short*)(Ob + (1u << 20));  // 16bh x 16seg x 128x128 bf16 [8 MiB]
    float* DS   = (float*)(SS + (4u << 20));  // 32K f32                   [128 KiB]
    short* WT   = (short*)(DS + 32768);       // 5 x 1M bf16 (W^T)         [10 MiB]
    short* Xb   = WT + (5u << 20);            // 1M bf16 (X cast)          [2 MiB]
    short* Obf  = QKVG;                       // alias Q (dead after corr_gnorm's QT use)

    cast_all<<<dim3(32, 32, 6), 256, 0, stream>>>(Wq, Wk, Wv, Wg, Wo, X, WT, Xb);
    proj_gemm<<<dim3(8, 16, 4), 256, 0, stream>>>(Xb, WT, QKVG);
    gk_proj<<<dim3(BT), 256, 0, stream>>>(Xb, Wgk1, Wgk2, bgk2, GK);
    scan_chunk<<<dim3(NSEG, NBH), 256, 0, stream>>>(
        QKVG, QKVG + (1u << 20), QKVG + (2u << 20), GK, Ob, SS, DS);
    stitch<<<dim3(8, NBH), 256, 0, stream>>>(SS, DS);
    corr_gnorm<<<dim3(NSEG, NBH), 256, 0, stream>>>(
        GK, SS, Ob, QKVG + (3u << 20), gnw, Obf);
    wo_gemm<<<dim3(16, 16), 256, 0, stream>>>(Obf, WT + (4u << 20), OUT);
}